// Round 13
// baseline (344.732 us; speedup 1.0000x reference)
//
#include <hip/hip_runtime.h>
#include <hip/hip_bf16.h>
#include <stdint.h>

#define S_LEN 2048
#define EMB   1024
#define NH    16
#define HD    64

typedef unsigned short u16;
typedef __attribute__((ext_vector_type(2))) float f32x2;
typedef __attribute__((ext_vector_type(4))) float f32x4;
typedef __attribute__((ext_vector_type(8))) short bf16x8;

typedef __attribute__((address_space(1))) const unsigned char gas_t;
typedef __attribute__((address_space(3))) unsigned char las_t;

static __device__ __forceinline__ void gld_lds16(const void* g, void* l) {
  __builtin_amdgcn_global_load_lds((gas_t*)g, (las_t*)l, 16, 0, 0);
}

static __device__ __forceinline__ u16 f2bf(float f) {
  unsigned int u = __builtin_bit_cast(unsigned int, f);
  u = u + 0x7fffu + ((u >> 16) & 1u);   // RNE; inputs are finite
  return (u16)(u >> 16);
}

// exp2 in one instruction (v_exp_f32 IS 2^x). HW-validated R4/R5.
static __device__ __forceinline__ float fexp2(float x) {
  float r;
  asm("v_exp_f32 %0, %1" : "=v"(r) : "v"(x));
  return r;
}

// pack 2 f32 -> 2 bf16 (RNE); lo = first arg. HW-validated R4/R5.
static __device__ __forceinline__ unsigned cvt_pk_bf16(float lo, float hi) {
  unsigned r;
  asm("v_cvt_pk_bf16_f32 %0, %1, %2" : "=v"(r) : "v"(lo), "v"(hi));
  return r;
}

// packed f32 add (CDNA2+ V_PK_ADD_F32; plain VALU, no cross-lane hazard).
static __device__ __forceinline__ f32x2 pk_add(f32x2 a, f32x2 b) {
  f32x2 r;
  asm("v_pk_add_f32 %0, %1, %2" : "=v"(r) : "v"(a), "v"(b));
  return r;
}

// Permlane swaps via BUILTINS (not inline asm) — R6/R7 lesson: the
// VALU->permlane RAW hazard is only mitigated for compiler-known instrs.
static __device__ __forceinline__ float red4rows_max(float x) {
  unsigned u = __builtin_bit_cast(unsigned, x);
  auto r = __builtin_amdgcn_permlane32_swap(u, u, false, false);
  float y = fmaxf(__builtin_bit_cast(float, (unsigned)r[0]),
                  __builtin_bit_cast(float, (unsigned)r[1]));
  unsigned v = __builtin_bit_cast(unsigned, y);
  auto r2 = __builtin_amdgcn_permlane16_swap(v, v, false, false);
  return fmaxf(__builtin_bit_cast(float, (unsigned)r2[0]),
               __builtin_bit_cast(float, (unsigned)r2[1]));
}
static __device__ __forceinline__ float red4rows_sum(float x) {
  unsigned u = __builtin_bit_cast(unsigned, x);
  auto r = __builtin_amdgcn_permlane32_swap(u, u, false, false);
  float y = __builtin_bit_cast(float, (unsigned)r[0]) +
            __builtin_bit_cast(float, (unsigned)r[1]);
  unsigned v = __builtin_bit_cast(unsigned, y);
  auto r2 = __builtin_amdgcn_permlane16_swap(v, v, false, false);
  return __builtin_bit_cast(float, (unsigned)r2[0]) +
         __builtin_bit_cast(float, (unsigned)r2[1]);
}

// ---------------- fused preprocessing: x->bf16 + both weight transposes -----
// grid 2048 x 256: [0,1024) cvt, [1024,1792) w_qkv T, [1792,2048) w_proj T.
__global__ __launch_bounds__(256) void k_prep(const float* __restrict__ x,
                                              u16* __restrict__ xb,
                                              const float* __restrict__ w_qkv,
                                              u16* __restrict__ wqkvT,
                                              const float* __restrict__ w_proj,
                                              u16* __restrict__ wprojT) {
  __shared__ u16 tile[64][68];
  const int bid = blockIdx.x;
  const int t = threadIdx.x;
  if (bid < 1024) {
    const int n4 = (8192 * 1024) / 4;
    int i = bid * 256 + t;
    for (; i < n4; i += 1024 * 256) {
      float4 f = ((const float4*)x)[i];
      ushort4 o;
      o.x = f2bf(f.x); o.y = f2bf(f.y); o.z = f2bf(f.z); o.w = f2bf(f.w);
      ((ushort4*)xb)[i] = o;
    }
    return;
  }
  const float* W;
  u16* WT;
  int c0, r0, K, N;
  if (bid < 1792) {
    const int idx = bid - 1024;            // 48 x 16 blocks
    W = w_qkv; WT = wqkvT; K = 1024; N = 3072;
    c0 = (idx % 48) * 64; r0 = (idx / 48) * 64;
  } else {
    const int idx = bid - 1792;            // 16 x 16 blocks
    W = w_proj; WT = wprojT; K = 1024; N = 1024;
    c0 = (idx & 15) * 64; r0 = (idx >> 4) * 64;
  }
  const int tr = t >> 4, tc4 = (t & 15) * 4;
#pragma unroll
  for (int i = 0; i < 4; i++) {
    const int r = tr + 16 * i;
    float4 f = *(const float4*)&W[(size_t)(r0 + r) * N + c0 + tc4];
    ushort4 o;
    o.x = f2bf(f.x); o.y = f2bf(f.y); o.z = f2bf(f.z); o.w = f2bf(f.w);
    *(ushort4*)&tile[r][tc4] = o;
  }
  __syncthreads();
  const int oc = t >> 2, or0 = (t & 3) * 16;
  u16 vals[16];
#pragma unroll
  for (int j = 0; j < 16; j++) vals[j] = tile[or0 + j][oc];
  u16* dst = &WT[(size_t)(c0 + oc) * K + r0 + or0];
  *(uint4*)dst = *(const uint4*)&vals[0];
  *(uint4*)(dst + 8) = *(const uint4*)&vals[8];
}

// ---------------- GEMM: C[M,N] = A[M,K](bf16) @ BT[N,K]^T + bias ----------------
// 128x128 tile, BK=32, 4 waves, double-buffered LDS, one barrier per k-step.
// T1 XCD-chunked swizzle (validated R12).
// MODE 0: scatter q/k bf16 [B,H,S,D], v bf16 [B,H,D,S] (transposed, vectorized).
// MODE 1: f32 out + bias.
template <int MODE>
__global__ __launch_bounds__(256) void k_gemm(const u16* __restrict__ A,
                                              const u16* __restrict__ BT,
                                              const float* __restrict__ bias,
                                              float* __restrict__ Cout,
                                              u16* __restrict__ q_ws,
                                              u16* __restrict__ k_ws,
                                              u16* __restrict__ v_t,
                                              int N, int K) {
  __shared__ u16 As[2][128 * 32];
  __shared__ u16 Bs[2][128 * 32];
  const int tid = threadIdx.x;
  const int w = tid >> 6, lane = tid & 63;
  const int wr = w >> 1, wc = w & 1;
  const int lrow = lane & 15, lk8 = (lane >> 4) * 8;
  const int orig = blockIdx.y * gridDim.x + blockIdx.x;
  const int total = gridDim.x * gridDim.y;
  const int wgid = (orig & 7) * (total >> 3) + (orig >> 3);
  const int bxn = wgid % gridDim.x;
  const int byn = wgid / gridDim.x;
  const int brow = byn * 128, bcol = bxn * 128;
  const int srow = lane >> 2;          // 0..15 within chunk
  const int scol = (lane & 3) * 8;     // 0,8,16,24

  const f32x4 zero = {0.f, 0.f, 0.f, 0.f};
  f32x4 acc[4][4];
#pragma unroll
  for (int m = 0; m < 4; m++)
#pragma unroll
    for (int n = 0; n < 4; n++) acc[m][n] = zero;

  auto stage = [&](int kt, int buf) {
#pragma unroll
    for (int i = 0; i < 2; i++) {
      const int c = w * 2 + i;               // chunk 0..7, 1KB each (linear LDS)
      const int row = c * 16 + srow;
      gld_lds16(&A[(size_t)(brow + row) * K + kt + scol], (void*)(&As[buf][c * 512]));
      gld_lds16(&BT[(size_t)(bcol + row) * K + kt + scol], (void*)(&Bs[buf][c * 512]));
    }
  };

  const int NK = K >> 5;
  stage(0, 0);
  __syncthreads();
  for (int it = 0; it < NK; ++it) {
    const int cur = it & 1;
    if (it + 1 < NK) stage((it + 1) << 5, cur ^ 1);
    bf16x8 af[4], bfr[4];
#pragma unroll
    for (int mt = 0; mt < 4; mt++)
      af[mt] = *(const bf16x8*)&As[cur][(wr * 64 + mt * 16 + lrow) * 32 + lk8];
#pragma unroll
    for (int nt = 0; nt < 4; nt++)
      bfr[nt] = *(const bf16x8*)&Bs[cur][(wc * 64 + nt * 16 + lrow) * 32 + lk8];
    __builtin_amdgcn_s_setprio(1);
#pragma unroll
    for (int mt = 0; mt < 4; mt++)
#pragma unroll
      for (int nt = 0; nt < 4; nt++)
        acc[mt][nt] = __builtin_amdgcn_mfma_f32_16x16x32_bf16(af[mt], bfr[nt],
                                                              acc[mt][nt], 0, 0, 0);
    __builtin_amdgcn_s_setprio(0);
    __syncthreads();
  }

  if constexpr (MODE == 0) {
    const int which = bcol >> 10;   // uniform per block (0=q, 1=k, 2=v)
#pragma unroll
    for (int mt = 0; mt < 4; mt++)
#pragma unroll
      for (int nt = 0; nt < 4; nt++) {
        const int col = bcol + wc * 64 + nt * 16 + lrow;
        const int e = col & 1023;
        const int h = e >> 6, d = e & 63;
        const int row0 = brow + wr * 64 + mt * 16 + (lane >> 4) * 4;
        const int b = row0 >> 11, s0 = row0 & 2047;
        const size_t bh = (size_t)(b * NH + h);
        const float bv = bias[col];
        if (which == 2) {
          ushort4 pk;
          pk.x = f2bf(acc[mt][nt][0] + bv);
          pk.y = f2bf(acc[mt][nt][1] + bv);
          pk.z = f2bf(acc[mt][nt][2] + bv);
          pk.w = f2bf(acc[mt][nt][3] + bv);
          *(ushort4*)&v_t[(bh * HD + d) * S_LEN + s0] = pk;
        } else {
          u16* dst = which ? k_ws : q_ws;
#pragma unroll
          for (int r = 0; r < 4; r++)
            dst[(bh * S_LEN + s0 + r) * HD + d] = f2bf(acc[mt][nt][r] + bv);
        }
      }
  } else {
#pragma unroll
    for (int mt = 0; mt < 4; mt++)
#pragma unroll
      for (int nt = 0; nt < 4; nt++)
#pragma unroll
        for (int r = 0; r < 4; r++) {
          const int row = brow + wr * 64 + mt * 16 + (lane >> 4) * 4 + r;
          const int col = bcol + wc * 64 + nt * 16 + lrow;
          Cout[(size_t)row * N + col] = acc[mt][nt][r] + bias[col];
        }
  }
}

// ---------------- causal flash attention ------------------------------------
// grid (16, B*H), 256 threads, pair-balanced {pr, 31-pr}.
// R13: NO LDS, NO BARRIERS in the KV loop. K/V fragments load global->reg
// directly (16x 16B/tile/wave): K/V is L2-resident after the R12 XCD remap
// (FETCH 24.6 MB), so the LDS round-trip + per-tile barrier convoy (the ~34%
// dead time) is pure overhead. Waves fully decouple; the 8 kf loads together
// touch the whole 64x128B tile so L1 serves repeat lanes. vf issued between
// QK and softmax so L2 latency hides under the softmax chain.
__global__ __launch_bounds__(256, 2) void k_attn(const u16* __restrict__ q_ws,
                                                 const u16* __restrict__ k_ws,
                                                 const u16* __restrict__ v_t,
                                                 u16* __restrict__ y) {
  const int tid = threadIdx.x;
  const int w = tid >> 6, lane = tid & 63;
  const int lrow = lane & 15, lk8 = (lane >> 4) * 8;
  const int g4 = (lane >> 4) * 4;
  // XCD-aware remap (R12): f = (bh&7) + 8*pr + 128*(bh>>3), bijective.
  const int f = blockIdx.y * 16 + blockIdx.x;
  const int pr = (f >> 3) & 15;            // 0..15
  const int bh = (f & 7) + ((f >> 7) << 3);
  const int tileA = pr, tileB = 31 - pr;   // tileA < tileB, work = const 33
  const size_t base = (size_t)bh * S_LEN * HD;
  const float SC = 0.125f * 1.4426950408889634f;  // D^-0.5 * log2(e)

  bf16x8 qfA[2], qfB[2];
#pragma unroll
  for (int ks = 0; ks < 2; ks++) {
    qfA[ks] = *(const bf16x8*)&q_ws[base + (size_t)(tileA * 64 + w * 16 + lrow) * HD + ks * 32 + lk8];
    qfB[ks] = *(const bf16x8*)&q_ws[base + (size_t)(tileB * 64 + w * 16 + lrow) * HD + ks * 32 + lk8];
  }

  const f32x4 zero = {0.f, 0.f, 0.f, 0.f};
  f32x4 oA[4], oB[4];                 // O[d][q]: d = dt*16 + g4 + r, q = lrow
#pragma unroll
  for (int dt = 0; dt < 4; dt++) { oA[dt] = zero; oB[dt] = zero; }
  float mA = -1e30f, lA = 0.f, mB = -1e30f, lB = 0.f;

  // QK^T only: sa[nt][r] = S[kv = nt*16+g4+r][q = lrow]
  auto qk = [&](const bf16x8 (&kf)[2][4], const bf16x8 (&qf)[2], f32x4 (&sa)[4]) {
#pragma unroll
    for (int nt = 0; nt < 4; nt++) sa[nt] = zero;
#pragma unroll
    for (int ks = 0; ks < 2; ks++)
#pragma unroll
      for (int nt = 0; nt < 4; nt++)
        sa[nt] = __builtin_amdgcn_mfma_f32_16x16x32_bf16(kf[ks][nt], qf[ks], sa[nt], 0, 0, 0);
  };

  // softmax + P-pack: consumes sa, produces pfrag; updates o/m/l (rescale).
  auto softmax = [&](f32x4 (&sa)[4], f32x4 (&o)[4], float& m_run, float& l_run,
                     bool maskDiag, bf16x8 (&pfrag)[2]) {
    float sv[4][4];
    if (maskDiag) {
#pragma unroll
      for (int nt = 0; nt < 4; nt++)
#pragma unroll
        for (int r = 0; r < 4; r++)
          sv[nt][r] = ((nt * 16 + g4 + r) > (w * 16 + lrow)) ? -3.0e38f : sa[nt][r];
    } else {
#pragma unroll
      for (int nt = 0; nt < 4; nt++)
#pragma unroll
        for (int r = 0; r < 4; r++) sv[nt][r] = sa[nt][r];
    }

    float mx = fmaxf(fmaxf(fmaxf(sv[0][0], sv[0][1]), fmaxf(sv[0][2], sv[0][3])),
                     fmaxf(fmaxf(sv[1][0], sv[1][1]), fmaxf(sv[1][2], sv[1][3])));
    mx = fmaxf(mx,
               fmaxf(fmaxf(fmaxf(sv[2][0], sv[2][1]), fmaxf(sv[2][2], sv[2][3])),
                     fmaxf(fmaxf(sv[3][0], sv[3][1]), fmaxf(sv[3][2], sv[3][3]))));
    mx = red4rows_max(mx);
    const float mxs = mx * SC;
    const bool nogrow = __all(mxs <= m_run + 8.0f);   // defer-max (T13)
    float mn = m_run;
    if (!nogrow) {
      mn = fmaxf(m_run, mxs);
      const float alpha = fexp2(m_run - mn);
      l_run *= alpha;
#pragma unroll
      for (int dt = 0; dt < 4; dt++) o[dt] *= alpha;
      m_run = mn;
    }
    const float nmn = -mn;
    f32x2 p2[4][2];
#pragma unroll
    for (int nt = 0; nt < 4; nt++)
#pragma unroll
      for (int h = 0; h < 2; h++) {
        const float a = fexp2(__builtin_fmaf(sv[nt][2 * h], SC, nmn));
        const float b = fexp2(__builtin_fmaf(sv[nt][2 * h + 1], SC, nmn));
        f32x2 p; p[0] = a; p[1] = b;
        p2[nt][h] = p;
      }
    f32x2 s0 = pk_add(p2[0][0], p2[0][1]);
    f32x2 s1 = pk_add(p2[1][0], p2[1][1]);
    f32x2 s2 = pk_add(p2[2][0], p2[2][1]);
    f32x2 s3 = pk_add(p2[3][0], p2[3][1]);
    s0 = pk_add(s0, s1);
    s2 = pk_add(s2, s3);
    s0 = pk_add(s0, s2);
    float sum = s0[0] + s0[1];
    sum = red4rows_sum(sum);
    l_run += sum;

    unsigned pk[4][2];
#pragma unroll
    for (int nt = 0; nt < 4; nt++) {
      pk[nt][0] = cvt_pk_bf16(p2[nt][0][0], p2[nt][0][1]);
      pk[nt][1] = cvt_pk_bf16(p2[nt][1][0], p2[nt][1][1]);
    }
    union { unsigned u[4]; bf16x8 v; } c0, c1;
    {
      auto r0 = __builtin_amdgcn_permlane32_swap(pk[0][0], pk[1][0], false, false);
      auto s0p = __builtin_amdgcn_permlane16_swap(r0[0], r0[1], false, false);
      auto r1 = __builtin_amdgcn_permlane32_swap(pk[0][1], pk[1][1], false, false);
      auto s1p = __builtin_amdgcn_permlane16_swap(r1[0], r1[1], false, false);
      c0.u[0] = s0p[0]; c0.u[1] = s1p[0]; c0.u[2] = s0p[1]; c0.u[3] = s1p[1];
      auto r2 = __builtin_amdgcn_permlane32_swap(pk[2][0], pk[3][0], false, false);
      auto s2p = __builtin_amdgcn_permlane16_swap(r2[0], r2[1], false, false);
      auto r3 = __builtin_amdgcn_permlane32_swap(pk[2][1], pk[3][1], false, false);
      auto s3p = __builtin_amdgcn_permlane16_swap(r3[0], r3[1], false, false);
      c1.u[0] = s2p[0]; c1.u[1] = s3p[0]; c1.u[2] = s2p[1]; c1.u[3] = s3p[1];
    }
    pfrag[0] = c0.v;
    pfrag[1] = c1.v;
  };

  for (int jb = 0; jb <= tileB; jb++) {
    const bool doA = (jb <= tileA);      // block-uniform

    // --- K fragments direct from global (L2-resident after XCD remap) ---
    // kf[ks][nt] = K[jb*64 + nt*16 + lrow][ks*32 + lk8 .. +7]
    const u16* kp = k_ws + base + ((size_t)(jb * 64) + lrow) * HD + lk8;
    bf16x8 kf[2][4];
#pragma unroll
    for (int ks = 0; ks < 2; ks++)
#pragma unroll
      for (int nt = 0; nt < 4; nt++)
        kf[ks][nt] = *(const bf16x8*)&kp[nt * (16 * HD) + ks * 32];

    f32x4 saB[4], saA[4];
    __builtin_amdgcn_s_setprio(1);
    qk(kf, qfB, saB);
    if (doA) qk(kf, qfA, saA);
    __builtin_amdgcn_s_setprio(0);

    // --- V fragments issued here; latency hides under the softmax chains ---
    // vf[ks][dt] = V^T[dt*16 + lrow][jb*64 + ks*32 + lk8 .. +7]
    const u16* vp = v_t + base + (size_t)lrow * S_LEN + jb * 64 + lk8;
    bf16x8 vf[2][4];
#pragma unroll
    for (int ks = 0; ks < 2; ks++)
#pragma unroll
      for (int dt = 0; dt < 4; dt++)
        vf[ks][dt] = *(const bf16x8*)&vp[(size_t)dt * (16 * S_LEN) + ks * 32];

    // --- two independent softmax chains (ILP) ---
    bf16x8 pfB[2], pfA[2];
    softmax(saB, oB, mB, lB, jb == tileB, pfB);
    if (doA) softmax(saA, oA, mA, lA, jb == tileA, pfA);

    // --- PV cluster ---
    __builtin_amdgcn_s_setprio(1);
#pragma unroll
    for (int ks = 0; ks < 2; ks++)
#pragma unroll
      for (int dt = 0; dt < 4; dt++)
        oB[dt] = __builtin_amdgcn_mfma_f32_16x16x32_bf16(vf[ks][dt], pfB[ks], oB[dt], 0, 0, 0);
    if (doA) {
#pragma unroll
      for (int ks = 0; ks < 2; ks++)
#pragma unroll
        for (int dt = 0; dt < 4; dt++)
          oA[dt] = __builtin_amdgcn_mfma_f32_16x16x32_bf16(vf[ks][dt], pfA[ks], oA[dt], 0, 0, 0);
    }
    __builtin_amdgcn_s_setprio(0);
  }

  const int b = bh >> 4, h = bh & 15;
  const float invA = 1.0f / lA;
  const float invB = 1.0f / lB;
  const int qgA = tileA * 64 + w * 16 + lrow;
  const int qgB = tileB * 64 + w * 16 + lrow;
#pragma unroll
  for (int dt = 0; dt < 4; dt++) {
    uint2 pa, pb;
    pa.x = cvt_pk_bf16(oA[dt][0] * invA, oA[dt][1] * invA);
    pa.y = cvt_pk_bf16(oA[dt][2] * invA, oA[dt][3] * invA);
    pb.x = cvt_pk_bf16(oB[dt][0] * invB, oB[dt][1] * invB);
    pb.y = cvt_pk_bf16(oB[dt][2] * invB, oB[dt][3] * invB);
    *(uint2*)&y[(size_t)(b * S_LEN + qgA) * EMB + h * HD + dt * 16 + g4] = pa;
    *(uint2*)&y[(size_t)(b * S_LEN + qgB) * EMB + h * HD + dt * 16 + g4] = pb;
  }
}

extern "C" void kernel_launch(void* const* d_in, const int* in_sizes, int n_in,
                              void* d_out, int out_size, void* d_ws, size_t ws_size,
                              hipStream_t stream) {
  const float* x      = (const float*)d_in[0];
  const float* w_qkv  = (const float*)d_in[1];
  const float* b_qkv  = (const float*)d_in[2];
  const float* w_proj = (const float*)d_in[3];
  const float* b_proj = (const float*)d_in[4];
  float* out = (float*)d_out;

  char* ws = (char*)d_ws;
  u16* wqkvT  = (u16*)(ws);                  // 3072x1024 bf16 (6 MB)
  u16* wprojT = (u16*)(ws + 6291456);        // 1024x1024 bf16 (2 MB)
  u16* xb     = (u16*)(ws + 8388608);        // 8192x1024 bf16 (16 MB), reused as y_att
  u16* q_ws   = (u16*)(ws + 25165824);       // [B,H,S,D] bf16 (16 MB)
  u16* k_ws   = (u16*)(ws + 41943040);       // [B,H,S,D]
  u16* v_t    = (u16*)(ws + 58720256);       // [B,H,D,S] (transposed!)  end: 72 MB
  u16* y_att  = xb;                          // x dead after GEMM1

  k_prep<<<dim3(2048), dim3(256), 0, stream>>>(x, xb, w_qkv, wqkvT, w_proj, wprojT);
  k_gemm<0><<<dim3(24, 64), dim3(256), 0, stream>>>(xb, wqkvT, b_qkv, nullptr,
                                                    q_ws, k_ws, v_t, 3072, 1024);
  k_attn<<<dim3(16, 64), dim3(256), 0, stream>>>(q_ws, k_ws, v_t, y_att);
  k_gemm<1><<<dim3(8, 64), dim3(256), 0, stream>>>(y_att, wprojT, b_proj, out,
                                                   nullptr, nullptr, nullptr, 1024, 1024);
}

// Round 14
// 184.704 us; speedup vs baseline: 1.8664x; 1.8664x over previous
//
#include <hip/hip_runtime.h>
#include <hip/hip_bf16.h>
#include <stdint.h>

#define S_LEN 2048
#define EMB   1024
#define NH    16
#define HD    64

typedef unsigned short u16;
typedef __attribute__((ext_vector_type(2))) float f32x2;
typedef __attribute__((ext_vector_type(4))) float f32x4;
typedef __attribute__((ext_vector_type(8))) short bf16x8;

typedef __attribute__((address_space(1))) const unsigned char gas_t;
typedef __attribute__((address_space(3))) unsigned char las_t;

static __device__ __forceinline__ void gld_lds16(const void* g, void* l) {
  __builtin_amdgcn_global_load_lds((gas_t*)g, (las_t*)l, 16, 0, 0);
}

static __device__ __forceinline__ u16 f2bf(float f) {
  unsigned int u = __builtin_bit_cast(unsigned int, f);
  u = u + 0x7fffu + ((u >> 16) & 1u);   // RNE; inputs are finite
  return (u16)(u >> 16);
}

// exp2 in one instruction (v_exp_f32 IS 2^x). HW-validated R4/R5.
static __device__ __forceinline__ float fexp2(float x) {
  float r;
  asm("v_exp_f32 %0, %1" : "=v"(r) : "v"(x));
  return r;
}

// pack 2 f32 -> 2 bf16 (RNE); lo = first arg. HW-validated R4/R5.
static __device__ __forceinline__ unsigned cvt_pk_bf16(float lo, float hi) {
  unsigned r;
  asm("v_cvt_pk_bf16_f32 %0, %1, %2" : "=v"(r) : "v"(lo), "v"(hi));
  return r;
}

// packed f32 add (CDNA2+ V_PK_ADD_F32; plain VALU, no cross-lane hazard).
static __device__ __forceinline__ f32x2 pk_add(f32x2 a, f32x2 b) {
  f32x2 r;
  asm("v_pk_add_f32 %0, %1, %2" : "=v"(r) : "v"(a), "v"(b));
  return r;
}

// Permlane swaps via BUILTINS (not inline asm) — R6/R7 lesson: the
// VALU->permlane RAW hazard is only mitigated for compiler-known instrs.
static __device__ __forceinline__ float red4rows_max(float x) {
  unsigned u = __builtin_bit_cast(unsigned, x);
  auto r = __builtin_amdgcn_permlane32_swap(u, u, false, false);
  float y = fmaxf(__builtin_bit_cast(float, (unsigned)r[0]),
                  __builtin_bit_cast(float, (unsigned)r[1]));
  unsigned v = __builtin_bit_cast(unsigned, y);
  auto r2 = __builtin_amdgcn_permlane16_swap(v, v, false, false);
  return fmaxf(__builtin_bit_cast(float, (unsigned)r2[0]),
               __builtin_bit_cast(float, (unsigned)r2[1]));
}
static __device__ __forceinline__ float red4rows_sum(float x) {
  unsigned u = __builtin_bit_cast(unsigned, x);
  auto r = __builtin_amdgcn_permlane32_swap(u, u, false, false);
  float y = __builtin_bit_cast(float, (unsigned)r[0]) +
            __builtin_bit_cast(float, (unsigned)r[1]);
  unsigned v = __builtin_bit_cast(unsigned, y);
  auto r2 = __builtin_amdgcn_permlane16_swap(v, v, false, false);
  return __builtin_bit_cast(float, (unsigned)r2[0]) +
         __builtin_bit_cast(float, (unsigned)r2[1]);
}

// ---------------- fused preprocessing: x->bf16 + both weight transposes -----
// grid 2048 x 256: [0,1024) cvt, [1024,1792) w_qkv T, [1792,2048) w_proj T.
__global__ __launch_bounds__(256) void k_prep(const float* __restrict__ x,
                                              u16* __restrict__ xb,
                                              const float* __restrict__ w_qkv,
                                              u16* __restrict__ wqkvT,
                                              const float* __restrict__ w_proj,
                                              u16* __restrict__ wprojT) {
  __shared__ u16 tile[64][68];
  const int bid = blockIdx.x;
  const int t = threadIdx.x;
  if (bid < 1024) {
    const int n4 = (8192 * 1024) / 4;
    int i = bid * 256 + t;
    for (; i < n4; i += 1024 * 256) {
      float4 f = ((const float4*)x)[i];
      ushort4 o;
      o.x = f2bf(f.x); o.y = f2bf(f.y); o.z = f2bf(f.z); o.w = f2bf(f.w);
      ((ushort4*)xb)[i] = o;
    }
    return;
  }
  const float* W;
  u16* WT;
  int c0, r0, K, N;
  if (bid < 1792) {
    const int idx = bid - 1024;            // 48 x 16 blocks
    W = w_qkv; WT = wqkvT; K = 1024; N = 3072;
    c0 = (idx % 48) * 64; r0 = (idx / 48) * 64;
  } else {
    const int idx = bid - 1792;            // 16 x 16 blocks
    W = w_proj; WT = wprojT; K = 1024; N = 1024;
    c0 = (idx & 15) * 64; r0 = (idx >> 4) * 64;
  }
  const int tr = t >> 4, tc4 = (t & 15) * 4;
#pragma unroll
  for (int i = 0; i < 4; i++) {
    const int r = tr + 16 * i;
    float4 f = *(const float4*)&W[(size_t)(r0 + r) * N + c0 + tc4];
    ushort4 o;
    o.x = f2bf(f.x); o.y = f2bf(f.y); o.z = f2bf(f.z); o.w = f2bf(f.w);
    *(ushort4*)&tile[r][tc4] = o;
  }
  __syncthreads();
  const int oc = t >> 2, or0 = (t & 3) * 16;
  u16 vals[16];
#pragma unroll
  for (int j = 0; j < 16; j++) vals[j] = tile[or0 + j][oc];
  u16* dst = &WT[(size_t)(c0 + oc) * K + r0 + or0];
  *(uint4*)dst = *(const uint4*)&vals[0];
  *(uint4*)(dst + 8) = *(const uint4*)&vals[8];
}

// ---------------- GEMM: C[M,N] = A[M,K](bf16) @ BT[N,K]^T + bias ----------------
// 128x128 tile, BK=32, 4 waves, double-buffered LDS, one barrier per k-step.
// T1 XCD-chunked swizzle (validated R12).
// MODE 0: scatter q/k bf16 [B,H,S,D], v bf16 [B,H,D,S] (transposed, vectorized).
// MODE 1: f32 out + bias.
template <int MODE>
__global__ __launch_bounds__(256) void k_gemm(const u16* __restrict__ A,
                                              const u16* __restrict__ BT,
                                              const float* __restrict__ bias,
                                              float* __restrict__ Cout,
                                              u16* __restrict__ q_ws,
                                              u16* __restrict__ k_ws,
                                              u16* __restrict__ v_t,
                                              int N, int K) {
  __shared__ u16 As[2][128 * 32];
  __shared__ u16 Bs[2][128 * 32];
  const int tid = threadIdx.x;
  const int w = tid >> 6, lane = tid & 63;
  const int wr = w >> 1, wc = w & 1;
  const int lrow = lane & 15, lk8 = (lane >> 4) * 8;
  const int orig = blockIdx.y * gridDim.x + blockIdx.x;
  const int total = gridDim.x * gridDim.y;
  const int wgid = (orig & 7) * (total >> 3) + (orig >> 3);
  const int bxn = wgid % gridDim.x;
  const int byn = wgid / gridDim.x;
  const int brow = byn * 128, bcol = bxn * 128;
  const int srow = lane >> 2;          // 0..15 within chunk
  const int scol = (lane & 3) * 8;     // 0,8,16,24

  const f32x4 zero = {0.f, 0.f, 0.f, 0.f};
  f32x4 acc[4][4];
#pragma unroll
  for (int m = 0; m < 4; m++)
#pragma unroll
    for (int n = 0; n < 4; n++) acc[m][n] = zero;

  auto stage = [&](int kt, int buf) {
#pragma unroll
    for (int i = 0; i < 2; i++) {
      const int c = w * 2 + i;               // chunk 0..7, 1KB each (linear LDS)
      const int row = c * 16 + srow;
      gld_lds16(&A[(size_t)(brow + row) * K + kt + scol], (void*)(&As[buf][c * 512]));
      gld_lds16(&BT[(size_t)(bcol + row) * K + kt + scol], (void*)(&Bs[buf][c * 512]));
    }
  };

  const int NK = K >> 5;
  stage(0, 0);
  __syncthreads();
  for (int it = 0; it < NK; ++it) {
    const int cur = it & 1;
    if (it + 1 < NK) stage((it + 1) << 5, cur ^ 1);
    bf16x8 af[4], bfr[4];
#pragma unroll
    for (int mt = 0; mt < 4; mt++)
      af[mt] = *(const bf16x8*)&As[cur][(wr * 64 + mt * 16 + lrow) * 32 + lk8];
#pragma unroll
    for (int nt = 0; nt < 4; nt++)
      bfr[nt] = *(const bf16x8*)&Bs[cur][(wc * 64 + nt * 16 + lrow) * 32 + lk8];
    __builtin_amdgcn_s_setprio(1);
#pragma unroll
    for (int mt = 0; mt < 4; mt++)
#pragma unroll
      for (int nt = 0; nt < 4; nt++)
        acc[mt][nt] = __builtin_amdgcn_mfma_f32_16x16x32_bf16(af[mt], bfr[nt],
                                                              acc[mt][nt], 0, 0, 0);
    __builtin_amdgcn_s_setprio(0);
    __syncthreads();
  }

  if constexpr (MODE == 0) {
    const int which = bcol >> 10;   // uniform per block (0=q, 1=k, 2=v)
#pragma unroll
    for (int mt = 0; mt < 4; mt++)
#pragma unroll
      for (int nt = 0; nt < 4; nt++) {
        const int col = bcol + wc * 64 + nt * 16 + lrow;
        const int e = col & 1023;
        const int h = e >> 6, d = e & 63;
        const int row0 = brow + wr * 64 + mt * 16 + (lane >> 4) * 4;
        const int b = row0 >> 11, s0 = row0 & 2047;
        const size_t bh = (size_t)(b * NH + h);
        const float bv = bias[col];
        if (which == 2) {
          ushort4 pk;
          pk.x = f2bf(acc[mt][nt][0] + bv);
          pk.y = f2bf(acc[mt][nt][1] + bv);
          pk.z = f2bf(acc[mt][nt][2] + bv);
          pk.w = f2bf(acc[mt][nt][3] + bv);
          *(ushort4*)&v_t[(bh * HD + d) * S_LEN + s0] = pk;
        } else {
          u16* dst = which ? k_ws : q_ws;
#pragma unroll
          for (int r = 0; r < 4; r++)
            dst[(bh * S_LEN + s0 + r) * HD + d] = f2bf(acc[mt][nt][r] + bv);
        }
      }
  } else {
#pragma unroll
    for (int mt = 0; mt < 4; mt++)
#pragma unroll
      for (int nt = 0; nt < 4; nt++)
#pragma unroll
        for (int r = 0; r < 4; r++) {
          const int row = brow + wr * 64 + mt * 16 + (lane >> 4) * 4 + r;
          const int col = bcol + wc * 64 + nt * 16 + lrow;
          Cout[(size_t)row * N + col] = acc[mt][nt][r] + bias[col];
        }
  }
}

// ---------------- causal flash attention ------------------------------------
// grid (16, B*H), 256 threads, pair-balanced {pr, 31-pr}, K/V double-buffered
// in LDS (R13 lesson: LDS staging amortizes tile loads across 4 waves AND
// gives one-full-tile prefetch distance; direct global->reg exposed ~300cyc
// L2 latency on every tile's critical path -> 3x regression. Keep staging.)
// SWAPPED QK^T -> S[kv][q]; P in registers via cvt_pk + permlane routing;
// PV = mfma(V^T, P) -> O[d][q].
// XCD-aware (pr,bh) remap (R12): XCD x gets all 16 pr-blocks of the 8 heads
// with bh%8==x -> K/V working set 4 MB/XCD = L2-resident (FETCH 147->24.6 MB).
__global__ __launch_bounds__(256, 2) void k_attn(const u16* __restrict__ q_ws,
                                                 const u16* __restrict__ k_ws,
                                                 const u16* __restrict__ v_t,
                                                 u16* __restrict__ y) {
  __shared__ u16 Kl[2][64 * 64];     // XOR-swizzled rows (16B blocks), [kv][d]
  __shared__ u16 Vl[2][64 * 64];     // XOR-swizzled rows, [d][kv]
  const int tid = threadIdx.x;
  const int w = tid >> 6, lane = tid & 63;
  const int lrow = lane & 15, lk8 = (lane >> 4) * 8;
  const int g4 = (lane >> 4) * 4;
  // XCD-aware remap: f = (bh&7) + 8*pr + 128*(bh>>3)  (bijective over 1024)
  const int f = blockIdx.y * 16 + blockIdx.x;
  const int pr = (f >> 3) & 15;            // 0..15
  const int bh = (f & 7) + ((f >> 7) << 3);
  const int tileA = pr, tileB = 31 - pr;   // tileA < tileB, work = const 33
  const size_t base = (size_t)bh * S_LEN * HD;
  const float SC = 0.125f * 1.4426950408889634f;  // D^-0.5 * log2(e)

  bf16x8 qfA[2], qfB[2];
#pragma unroll
  for (int ks = 0; ks < 2; ks++) {
    qfA[ks] = *(const bf16x8*)&q_ws[base + (size_t)(tileA * 64 + w * 16 + lrow) * HD + ks * 32 + lk8];
    qfB[ks] = *(const bf16x8*)&q_ws[base + (size_t)(tileB * 64 + w * 16 + lrow) * HD + ks * 32 + lk8];
  }

  const f32x4 zero = {0.f, 0.f, 0.f, 0.f};
  f32x4 oA[4], oB[4];                 // O[d][q]: d = dt*16 + g4 + r, q = lrow
#pragma unroll
  for (int dt = 0; dt < 4; dt++) { oA[dt] = zero; oB[dt] = zero; }
  float mA = -1e30f, lA = 0.f, mB = -1e30f, lB = 0.f;

  auto stage = [&](int jb, int buf) {
#pragma unroll
    for (int i = 0; i < 2; i++) {
      const int c = w * 2 + i;
      const int row = c * 8 + (lane >> 3);
      const int blk = (lane & 7) ^ (row & 7);
      gld_lds16(&k_ws[base + (size_t)(jb * 64 + row) * HD + blk * 8],
                (void*)(&Kl[buf][c * 512]));
      gld_lds16(&v_t[base + (size_t)row * S_LEN + jb * 64 + blk * 8],
                (void*)(&Vl[buf][c * 512]));
    }
  };

  // QK^T only: sa[nt][r] = S[kv = nt*16+g4+r][q = lrow]
  auto qk = [&](const bf16x8 (&kf)[2][4], const bf16x8 (&qf)[2], f32x4 (&sa)[4]) {
#pragma unroll
    for (int nt = 0; nt < 4; nt++) sa[nt] = zero;
#pragma unroll
    for (int ks = 0; ks < 2; ks++)
#pragma unroll
      for (int nt = 0; nt < 4; nt++)
        sa[nt] = __builtin_amdgcn_mfma_f32_16x16x32_bf16(kf[ks][nt], qf[ks], sa[nt], 0, 0, 0);
  };

  // softmax + P-pack: consumes sa, produces pfrag; updates o/m/l (rescale).
  auto softmax = [&](f32x4 (&sa)[4], f32x4 (&o)[4], float& m_run, float& l_run,
                     bool maskDiag, bf16x8 (&pfrag)[2]) {
    float sv[4][4];
    if (maskDiag) {
#pragma unroll
      for (int nt = 0; nt < 4; nt++)
#pragma unroll
        for (int r = 0; r < 4; r++)
          sv[nt][r] = ((nt * 16 + g4 + r) > (w * 16 + lrow)) ? -3.0e38f : sa[nt][r];
    } else {
#pragma unroll
      for (int nt = 0; nt < 4; nt++)
#pragma unroll
        for (int r = 0; r < 4; r++) sv[nt][r] = sa[nt][r];
    }

    float mx = fmaxf(fmaxf(fmaxf(sv[0][0], sv[0][1]), fmaxf(sv[0][2], sv[0][3])),
                     fmaxf(fmaxf(sv[1][0], sv[1][1]), fmaxf(sv[1][2], sv[1][3])));
    mx = fmaxf(mx,
               fmaxf(fmaxf(fmaxf(sv[2][0], sv[2][1]), fmaxf(sv[2][2], sv[2][3])),
                     fmaxf(fmaxf(sv[3][0], sv[3][1]), fmaxf(sv[3][2], sv[3][3]))));
    mx = red4rows_max(mx);
    const float mxs = mx * SC;
    const bool nogrow = __all(mxs <= m_run + 8.0f);   // defer-max (T13)
    float mn = m_run;
    if (!nogrow) {
      mn = fmaxf(m_run, mxs);
      const float alpha = fexp2(m_run - mn);
      l_run *= alpha;
#pragma unroll
      for (int dt = 0; dt < 4; dt++) o[dt] *= alpha;
      m_run = mn;
    }
    const float nmn = -mn;
    f32x2 p2[4][2];
#pragma unroll
    for (int nt = 0; nt < 4; nt++)
#pragma unroll
      for (int h = 0; h < 2; h++) {
        const float a = fexp2(__builtin_fmaf(sv[nt][2 * h], SC, nmn));
        const float b = fexp2(__builtin_fmaf(sv[nt][2 * h + 1], SC, nmn));
        f32x2 p; p[0] = a; p[1] = b;
        p2[nt][h] = p;
      }
    f32x2 s0 = pk_add(p2[0][0], p2[0][1]);
    f32x2 s1 = pk_add(p2[1][0], p2[1][1]);
    f32x2 s2 = pk_add(p2[2][0], p2[2][1]);
    f32x2 s3 = pk_add(p2[3][0], p2[3][1]);
    s0 = pk_add(s0, s1);
    s2 = pk_add(s2, s3);
    s0 = pk_add(s0, s2);
    float sum = s0[0] + s0[1];
    sum = red4rows_sum(sum);
    l_run += sum;

    unsigned pk[4][2];
#pragma unroll
    for (int nt = 0; nt < 4; nt++) {
      pk[nt][0] = cvt_pk_bf16(p2[nt][0][0], p2[nt][0][1]);
      pk[nt][1] = cvt_pk_bf16(p2[nt][1][0], p2[nt][1][1]);
    }
    union { unsigned u[4]; bf16x8 v; } c0, c1;
    {
      auto r0 = __builtin_amdgcn_permlane32_swap(pk[0][0], pk[1][0], false, false);
      auto s0p = __builtin_amdgcn_permlane16_swap(r0[0], r0[1], false, false);
      auto r1 = __builtin_amdgcn_permlane32_swap(pk[0][1], pk[1][1], false, false);
      auto s1p = __builtin_amdgcn_permlane16_swap(r1[0], r1[1], false, false);
      c0.u[0] = s0p[0]; c0.u[1] = s1p[0]; c0.u[2] = s0p[1]; c0.u[3] = s1p[1];
      auto r2 = __builtin_amdgcn_permlane32_swap(pk[2][0], pk[3][0], false, false);
      auto s2p = __builtin_amdgcn_permlane16_swap(r2[0], r2[1], false, false);
      auto r3 = __builtin_amdgcn_permlane32_swap(pk[2][1], pk[3][1], false, false);
      auto s3p = __builtin_amdgcn_permlane16_swap(r3[0], r3[1], false, false);
      c1.u[0] = s2p[0]; c1.u[1] = s3p[0]; c1.u[2] = s2p[1]; c1.u[3] = s3p[1];
    }
    pfrag[0] = c0.v;
    pfrag[1] = c1.v;
  };

  stage(0, 0);
  __syncthreads();
  for (int jb = 0; jb <= tileB; jb++) {
    const int cur = jb & 1;
    if (jb < tileB) stage(jb + 1, cur ^ 1);
    const bool doA = (jb <= tileA);      // block-uniform

    // --- QK cluster (kf live only here) ---
    bf16x8 kf[2][4];
#pragma unroll
    for (int ks = 0; ks < 2; ks++)
#pragma unroll
      for (int nt = 0; nt < 4; nt++) {
        const int kvr = nt * 16 + lrow;
        const int blk = (ks * 4 + (lane >> 4)) ^ (kvr & 7);
        kf[ks][nt] = *(const bf16x8*)&Kl[cur][kvr * 64 + blk * 8];
      }
    f32x4 saB[4], saA[4];
    __builtin_amdgcn_s_setprio(1);
    qk(kf, qfB, saB);
    if (doA) qk(kf, qfA, saA);
    __builtin_amdgcn_s_setprio(0);

    // --- two independent softmax chains (ILP) ---
    bf16x8 pfB[2], pfA[2];
    softmax(saB, oB, mB, lB, jb == tileB, pfB);
    if (doA) softmax(saA, oA, mA, lA, jb == tileA, pfA);

    // --- vf load just before PV (short live range) ---
    bf16x8 vf[2][4];
#pragma unroll
    for (int ks = 0; ks < 2; ks++)
#pragma unroll
      for (int dt = 0; dt < 4; dt++) {
        const int vr = dt * 16 + lrow;
        const int vblk = (ks * 4 + (lane >> 4)) ^ (vr & 7);
        vf[ks][dt] = *(const bf16x8*)&Vl[cur][vr * 64 + vblk * 8];
      }

    // --- PV cluster ---
    __builtin_amdgcn_s_setprio(1);
#pragma unroll
    for (int ks = 0; ks < 2; ks++)
#pragma unroll
      for (int dt = 0; dt < 4; dt++)
        oB[dt] = __builtin_amdgcn_mfma_f32_16x16x32_bf16(vf[ks][dt], pfB[ks], oB[dt], 0, 0, 0);
    if (doA) {
#pragma unroll
      for (int ks = 0; ks < 2; ks++)
#pragma unroll
        for (int dt = 0; dt < 4; dt++)
          oA[dt] = __builtin_amdgcn_mfma_f32_16x16x32_bf16(vf[ks][dt], pfA[ks], oA[dt], 0, 0, 0);
    }
    __builtin_amdgcn_s_setprio(0);
    __syncthreads();
  }

  const int b = bh >> 4, h = bh & 15;
  const float invA = 1.0f / lA;
  const float invB = 1.0f / lB;
  const int qgA = tileA * 64 + w * 16 + lrow;
  const int qgB = tileB * 64 + w * 16 + lrow;
#pragma unroll
  for (int dt = 0; dt < 4; dt++) {
    uint2 pa, pb;
    pa.x = cvt_pk_bf16(oA[dt][0] * invA, oA[dt][1] * invA);
    pa.y = cvt_pk_bf16(oA[dt][2] * invA, oA[dt][3] * invA);
    pb.x = cvt_pk_bf16(oB[dt][0] * invB, oB[dt][1] * invB);
    pb.y = cvt_pk_bf16(oB[dt][2] * invB, oB[dt][3] * invB);
    *(uint2*)&y[(size_t)(b * S_LEN + qgA) * EMB + h * HD + dt * 16 + g4] = pa;
    *(uint2*)&y[(size_t)(b * S_LEN + qgB) * EMB + h * HD + dt * 16 + g4] = pb;
  }
}

extern "C" void kernel_launch(void* const* d_in, const int* in_sizes, int n_in,
                              void* d_out, int out_size, void* d_ws, size_t ws_size,
                              hipStream_t stream) {
  const float* x      = (const float*)d_in[0];
  const float* w_qkv  = (const float*)d_in[1];
  const float* b_qkv  = (const float*)d_in[2];
  const float* w_proj = (const float*)d_in[3];
  const float* b_proj = (const float*)d_in[4];
  float* out = (float*)d_out;

  char* ws = (char*)d_ws;
  u16* wqkvT  = (u16*)(ws);                  // 3072x1024 bf16 (6 MB)
  u16* wprojT = (u16*)(ws + 6291456);        // 1024x1024 bf16 (2 MB)
  u16* xb     = (u16*)(ws + 8388608);        // 8192x1024 bf16 (16 MB), reused as y_att
  u16* q_ws   = (u16*)(ws + 25165824);       // [B,H,S,D] bf16 (16 MB)
  u16* k_ws   = (u16*)(ws + 41943040);       // [B,H,S,D]
  u16* v_t    = (u16*)(ws + 58720256);       // [B,H,D,S] (transposed!)  end: 72 MB
  u16* y_att  = xb;                          // x dead after GEMM1

  k_prep<<<dim3(2048), dim3(256), 0, stream>>>(x, xb, w_qkv, wqkvT, w_proj, wprojT);
  k_gemm<0><<<dim3(24, 64), dim3(256), 0, stream>>>(xb, wqkvT, b_qkv, nullptr,
                                                    q_ws, k_ws, v_t, 3072, 1024);
  k_attn<<<dim3(16, 64), dim3(256), 0, stream>>>(q_ws, k_ws, v_t, y_att);
  k_gemm<1><<<dim3(8, 64), dim3(256), 0, stream>>>(y_att, wprojT, b_proj, out,
                                                   nullptr, nullptr, nullptr, 1024, 1024);
}

// Round 16
// 183.363 us; speedup vs baseline: 1.8801x; 1.0073x over previous
//
#include <hip/hip_runtime.h>
#include <hip/hip_bf16.h>
#include <stdint.h>

#define S_LEN 2048
#define EMB   1024
#define NH    16
#define HD    64

typedef unsigned short u16;
typedef __attribute__((ext_vector_type(2))) float f32x2;
typedef __attribute__((ext_vector_type(4))) float f32x4;
typedef __attribute__((ext_vector_type(8))) short bf16x8;

typedef __attribute__((address_space(1))) const unsigned char gas_t;
typedef __attribute__((address_space(3))) unsigned char las_t;

static __device__ __forceinline__ void gld_lds16(const void* g, void* l) {
  __builtin_amdgcn_global_load_lds((gas_t*)g, (las_t*)l, 16, 0, 0);
}

static __device__ __forceinline__ u16 f2bf(float f) {
  unsigned int u = __builtin_bit_cast(unsigned int, f);
  u = u + 0x7fffu + ((u >> 16) & 1u);   // RNE; inputs are finite
  return (u16)(u >> 16);
}

// exp2 in one instruction (v_exp_f32 IS 2^x). HW-validated R4/R5.
static __device__ __forceinline__ float fexp2(float x) {
  float r;
  asm("v_exp_f32 %0, %1" : "=v"(r) : "v"(x));
  return r;
}

// pack 2 f32 -> 2 bf16 (RNE); lo = first arg. HW-validated R4/R5.
static __device__ __forceinline__ unsigned cvt_pk_bf16(float lo, float hi) {
  unsigned r;
  asm("v_cvt_pk_bf16_f32 %0, %1, %2" : "=v"(r) : "v"(lo), "v"(hi));
  return r;
}

// 3-input max: genuine gfx9+ VOP3 (ISA §3). Plain VALU, no hazard concern.
// R15 lesson: v_pk_max_f32 does NOT exist on gfx950 (packed f32 is only
// add/mul/fma; pk_max is f16/i16/u16 only) — ISA-check each op individually.
static __device__ __forceinline__ float max3(float a, float b, float c) {
  float r;
  asm("v_max3_f32 %0, %1, %2, %3" : "=v"(r) : "v"(a), "v"(b), "v"(c));
  return r;
}

// Packed f32 VOP3P ops that DO exist on gfx950 (add validated R10 at runtime;
// mul/fma compile-validated R15 — only pk_max errored).
static __device__ __forceinline__ f32x2 pk_add(f32x2 a, f32x2 b) {
  f32x2 r;
  asm("v_pk_add_f32 %0, %1, %2" : "=v"(r) : "v"(a), "v"(b));
  return r;
}
static __device__ __forceinline__ f32x2 pk_mul(f32x2 a, f32x2 b) {
  f32x2 r;
  asm("v_pk_mul_f32 %0, %1, %2" : "=v"(r) : "v"(a), "v"(b));
  return r;
}
static __device__ __forceinline__ f32x2 pk_fma(f32x2 a, f32x2 b, f32x2 c) {
  f32x2 r;
  asm("v_pk_fma_f32 %0, %1, %2, %3" : "=v"(r) : "v"(a), "v"(b), "v"(c));
  return r;
}
#define HALF0(v) __builtin_shufflevector(v, v, 0, 1)
#define HALF1(v) __builtin_shufflevector(v, v, 2, 3)

// Permlane swaps via BUILTINS (not inline asm) — R6/R7 lesson: the
// VALU->permlane RAW hazard is only mitigated for compiler-known instrs.
static __device__ __forceinline__ float red4rows_max(float x) {
  unsigned u = __builtin_bit_cast(unsigned, x);
  auto r = __builtin_amdgcn_permlane32_swap(u, u, false, false);
  float y = fmaxf(__builtin_bit_cast(float, (unsigned)r[0]),
                  __builtin_bit_cast(float, (unsigned)r[1]));
  unsigned v = __builtin_bit_cast(unsigned, y);
  auto r2 = __builtin_amdgcn_permlane16_swap(v, v, false, false);
  return fmaxf(__builtin_bit_cast(float, (unsigned)r2[0]),
               __builtin_bit_cast(float, (unsigned)r2[1]));
}
static __device__ __forceinline__ float red4rows_sum(float x) {
  unsigned u = __builtin_bit_cast(unsigned, x);
  auto r = __builtin_amdgcn_permlane32_swap(u, u, false, false);
  float y = __builtin_bit_cast(float, (unsigned)r[0]) +
            __builtin_bit_cast(float, (unsigned)r[1]);
  unsigned v = __builtin_bit_cast(unsigned, y);
  auto r2 = __builtin_amdgcn_permlane16_swap(v, v, false, false);
  return __builtin_bit_cast(float, (unsigned)r2[0]) +
         __builtin_bit_cast(float, (unsigned)r2[1]);
}

// ---------------- fused preprocessing: x->bf16 + both weight transposes -----
// grid 2048 x 256: [0,1024) cvt, [1024,1792) w_qkv T, [1792,2048) w_proj T.
__global__ __launch_bounds__(256) void k_prep(const float* __restrict__ x,
                                              u16* __restrict__ xb,
                                              const float* __restrict__ w_qkv,
                                              u16* __restrict__ wqkvT,
                                              const float* __restrict__ w_proj,
                                              u16* __restrict__ wprojT) {
  __shared__ u16 tile[64][68];
  const int bid = blockIdx.x;
  const int t = threadIdx.x;
  if (bid < 1024) {
    const int n4 = (8192 * 1024) / 4;
    int i = bid * 256 + t;
    for (; i < n4; i += 1024 * 256) {
      float4 f = ((const float4*)x)[i];
      ushort4 o;
      o.x = f2bf(f.x); o.y = f2bf(f.y); o.z = f2bf(f.z); o.w = f2bf(f.w);
      ((ushort4*)xb)[i] = o;
    }
    return;
  }
  const float* W;
  u16* WT;
  int c0, r0, K, N;
  if (bid < 1792) {
    const int idx = bid - 1024;            // 48 x 16 blocks
    W = w_qkv; WT = wqkvT; K = 1024; N = 3072;
    c0 = (idx % 48) * 64; r0 = (idx / 48) * 64;
  } else {
    const int idx = bid - 1792;            // 16 x 16 blocks
    W = w_proj; WT = wprojT; K = 1024; N = 1024;
    c0 = (idx & 15) * 64; r0 = (idx >> 4) * 64;
  }
  const int tr = t >> 4, tc4 = (t & 15) * 4;
#pragma unroll
  for (int i = 0; i < 4; i++) {
    const int r = tr + 16 * i;
    float4 f = *(const float4*)&W[(size_t)(r0 + r) * N + c0 + tc4];
    ushort4 o;
    o.x = f2bf(f.x); o.y = f2bf(f.y); o.z = f2bf(f.z); o.w = f2bf(f.w);
    *(ushort4*)&tile[r][tc4] = o;
  }
  __syncthreads();
  const int oc = t >> 2, or0 = (t & 3) * 16;
  u16 vals[16];
#pragma unroll
  for (int j = 0; j < 16; j++) vals[j] = tile[or0 + j][oc];
  u16* dst = &WT[(size_t)(c0 + oc) * K + r0 + or0];
  *(uint4*)dst = *(const uint4*)&vals[0];
  *(uint4*)(dst + 8) = *(const uint4*)&vals[8];
}

// ---------------- GEMM: C[M,N] = A[M,K](bf16) @ BT[N,K]^T + bias ----------------
// 128x128 tile, BK=32, 4 waves, double-buffered LDS, one barrier per k-step.
// T1 XCD-chunked swizzle (validated R12).
// MODE 0: scatter q/k bf16 [B,H,S,D], v bf16 [B,H,D,S] (transposed, vectorized).
// MODE 1: f32 out + bias.
template <int MODE>
__global__ __launch_bounds__(256) void k_gemm(const u16* __restrict__ A,
                                              const u16* __restrict__ BT,
                                              const float* __restrict__ bias,
                                              float* __restrict__ Cout,
                                              u16* __restrict__ q_ws,
                                              u16* __restrict__ k_ws,
                                              u16* __restrict__ v_t,
                                              int N, int K) {
  __shared__ u16 As[2][128 * 32];
  __shared__ u16 Bs[2][128 * 32];
  const int tid = threadIdx.x;
  const int w = tid >> 6, lane = tid & 63;
  const int wr = w >> 1, wc = w & 1;
  const int lrow = lane & 15, lk8 = (lane >> 4) * 8;
  const int orig = blockIdx.y * gridDim.x + blockIdx.x;
  const int total = gridDim.x * gridDim.y;
  const int wgid = (orig & 7) * (total >> 3) + (orig >> 3);
  const int bxn = wgid % gridDim.x;
  const int byn = wgid / gridDim.x;
  const int brow = byn * 128, bcol = bxn * 128;
  const int srow = lane >> 2;          // 0..15 within chunk
  const int scol = (lane & 3) * 8;     // 0,8,16,24

  const f32x4 zero = {0.f, 0.f, 0.f, 0.f};
  f32x4 acc[4][4];
#pragma unroll
  for (int m = 0; m < 4; m++)
#pragma unroll
    for (int n = 0; n < 4; n++) acc[m][n] = zero;

  auto stage = [&](int kt, int buf) {
#pragma unroll
    for (int i = 0; i < 2; i++) {
      const int c = w * 2 + i;               // chunk 0..7, 1KB each (linear LDS)
      const int row = c * 16 + srow;
      gld_lds16(&A[(size_t)(brow + row) * K + kt + scol], (void*)(&As[buf][c * 512]));
      gld_lds16(&BT[(size_t)(bcol + row) * K + kt + scol], (void*)(&Bs[buf][c * 512]));
    }
  };

  const int NK = K >> 5;
  stage(0, 0);
  __syncthreads();
  for (int it = 0; it < NK; ++it) {
    const int cur = it & 1;
    if (it + 1 < NK) stage((it + 1) << 5, cur ^ 1);
    bf16x8 af[4], bfr[4];
#pragma unroll
    for (int mt = 0; mt < 4; mt++)
      af[mt] = *(const bf16x8*)&As[cur][(wr * 64 + mt * 16 + lrow) * 32 + lk8];
#pragma unroll
    for (int nt = 0; nt < 4; nt++)
      bfr[nt] = *(const bf16x8*)&Bs[cur][(wc * 64 + nt * 16 + lrow) * 32 + lk8];
    __builtin_amdgcn_s_setprio(1);
#pragma unroll
    for (int mt = 0; mt < 4; mt++)
#pragma unroll
      for (int nt = 0; nt < 4; nt++)
        acc[mt][nt] = __builtin_amdgcn_mfma_f32_16x16x32_bf16(af[mt], bfr[nt],
                                                              acc[mt][nt], 0, 0, 0);
    __builtin_amdgcn_s_setprio(0);
    __syncthreads();
  }

  if constexpr (MODE == 0) {
    const int which = bcol >> 10;   // uniform per block (0=q, 1=k, 2=v)
#pragma unroll
    for (int mt = 0; mt < 4; mt++)
#pragma unroll
      for (int nt = 0; nt < 4; nt++) {
        const int col = bcol + wc * 64 + nt * 16 + lrow;
        const int e = col & 1023;
        const int h = e >> 6, d = e & 63;
        const int row0 = brow + wr * 64 + mt * 16 + (lane >> 4) * 4;
        const int b = row0 >> 11, s0 = row0 & 2047;
        const size_t bh = (size_t)(b * NH + h);
        const float bv = bias[col];
        if (which == 2) {
          ushort4 pk;
          pk.x = f2bf(acc[mt][nt][0] + bv);
          pk.y = f2bf(acc[mt][nt][1] + bv);
          pk.z = f2bf(acc[mt][nt][2] + bv);
          pk.w = f2bf(acc[mt][nt][3] + bv);
          *(ushort4*)&v_t[(bh * HD + d) * S_LEN + s0] = pk;
        } else {
          u16* dst = which ? k_ws : q_ws;
#pragma unroll
          for (int r = 0; r < 4; r++)
            dst[(bh * S_LEN + s0 + r) * HD + d] = f2bf(acc[mt][nt][r] + bv);
        }
      }
  } else {
#pragma unroll
    for (int mt = 0; mt < 4; mt++)
#pragma unroll
      for (int nt = 0; nt < 4; nt++)
#pragma unroll
        for (int r = 0; r < 4; r++) {
          const int row = brow + wr * 64 + mt * 16 + (lane >> 4) * 4 + r;
          const int col = bcol + wc * 64 + nt * 16 + lrow;
          Cout[(size_t)row * N + col] = acc[mt][nt][r] + bias[col];
        }
  }
}

// ---------------- causal flash attention ------------------------------------
// grid (16, B*H), 256 threads, pair-balanced {pr, 31-pr}, K/V double-buffered
// in LDS (R13 lesson: staging amortizes loads across waves + gives full-tile
// prefetch distance). SWAPPED QK^T -> S[kv][q]; P in registers via cvt_pk +
// permlane routing; PV = mfma(V^T, P) -> O[d][q]. XCD remap (R12).
// R16: softmax VALU cut — in-place mask on sa (no sv copy), v_max3 tree
// (7 max3 + 1 fmax vs 15 fmax), packed exp2 args (8 pk_fma), packed rescale.
__global__ __launch_bounds__(256, 2) void k_attn(const u16* __restrict__ q_ws,
                                                 const u16* __restrict__ k_ws,
                                                 const u16* __restrict__ v_t,
                                                 u16* __restrict__ y) {
  __shared__ u16 Kl[2][64 * 64];     // XOR-swizzled rows (16B blocks), [kv][d]
  __shared__ u16 Vl[2][64 * 64];     // XOR-swizzled rows, [d][kv]
  const int tid = threadIdx.x;
  const int w = tid >> 6, lane = tid & 63;
  const int lrow = lane & 15, lk8 = (lane >> 4) * 8;
  const int g4 = (lane >> 4) * 4;
  const int mthr = w * 16 + lrow - g4;     // mask: kv-local nt*16+r > mthr
  // XCD-aware remap: f = (bh&7) + 8*pr + 128*(bh>>3)  (bijective over 1024)
  const int f = blockIdx.y * 16 + blockIdx.x;
  const int pr = (f >> 3) & 15;            // 0..15
  const int bh = (f & 7) + ((f >> 7) << 3);
  const int tileA = pr, tileB = 31 - pr;   // tileA < tileB, work = const 33
  const size_t base = (size_t)bh * S_LEN * HD;
  const float SC = 0.125f * 1.4426950408889634f;  // D^-0.5 * log2(e)

  bf16x8 qfA[2], qfB[2];
#pragma unroll
  for (int ks = 0; ks < 2; ks++) {
    qfA[ks] = *(const bf16x8*)&q_ws[base + (size_t)(tileA * 64 + w * 16 + lrow) * HD + ks * 32 + lk8];
    qfB[ks] = *(const bf16x8*)&q_ws[base + (size_t)(tileB * 64 + w * 16 + lrow) * HD + ks * 32 + lk8];
  }

  const f32x4 zero = {0.f, 0.f, 0.f, 0.f};
  f32x4 oA[4], oB[4];                 // O[d][q]: d = dt*16 + g4 + r, q = lrow
#pragma unroll
  for (int dt = 0; dt < 4; dt++) { oA[dt] = zero; oB[dt] = zero; }
  float mA = -1e30f, lA = 0.f, mB = -1e30f, lB = 0.f;

  auto stage = [&](int jb, int buf) {
#pragma unroll
    for (int i = 0; i < 2; i++) {
      const int c = w * 2 + i;
      const int row = c * 8 + (lane >> 3);
      const int blk = (lane & 7) ^ (row & 7);
      gld_lds16(&k_ws[base + (size_t)(jb * 64 + row) * HD + blk * 8],
                (void*)(&Kl[buf][c * 512]));
      gld_lds16(&v_t[base + (size_t)row * S_LEN + jb * 64 + blk * 8],
                (void*)(&Vl[buf][c * 512]));
    }
  };

  // QK^T only: sa[nt][r] = S[kv = nt*16+g4+r][q = lrow]
  auto qk = [&](const bf16x8 (&kf)[2][4], const bf16x8 (&qf)[2], f32x4 (&sa)[4]) {
#pragma unroll
    for (int nt = 0; nt < 4; nt++) sa[nt] = zero;
#pragma unroll
    for (int ks = 0; ks < 2; ks++)
#pragma unroll
      for (int nt = 0; nt < 4; nt++)
        sa[nt] = __builtin_amdgcn_mfma_f32_16x16x32_bf16(kf[ks][nt], qf[ks], sa[nt], 0, 0, 0);
  };

  // softmax + P-pack: mutates sa in place, produces pfrag; updates o/m/l.
  auto softmax = [&](f32x4 (&sa)[4], f32x4 (&o)[4], float& m_run, float& l_run,
                     bool maskDiag, bf16x8 (&pfrag)[2]) {
    if (maskDiag) {
#pragma unroll
      for (int nt = 0; nt < 4; nt++)
#pragma unroll
        for (int r = 0; r < 4; r++)
          if (nt * 16 + r > mthr) sa[nt][r] = -3.0e38f;
    }

    // v_max3 tree: 7 max3 + 1 fmax (was 15 fmax); exact max, order-free
    const float m0 = max3(sa[0][0], sa[0][1], sa[0][2]);
    const float m1 = max3(sa[0][3], sa[1][0], sa[1][1]);
    const float m2 = max3(sa[1][2], sa[1][3], sa[2][0]);
    const float m3 = max3(sa[2][1], sa[2][2], sa[2][3]);
    const float m4 = max3(sa[3][0], sa[3][1], sa[3][2]);
    const float m5 = max3(m0, m1, m2);
    const float m6 = max3(m3, m4, sa[3][3]);
    float mx = fmaxf(m5, m6);
    mx = red4rows_max(mx);
    const float mxs = mx * SC;
    const bool nogrow = __all(mxs <= m_run + 8.0f);   // defer-max (T13)
    float mn = m_run;
    if (!nogrow) {
      mn = fmaxf(m_run, mxs);
      const float alpha = fexp2(m_run - mn);
      l_run *= alpha;
      const f32x2 al2 = {alpha, alpha};
#pragma unroll
      for (int dt = 0; dt < 4; dt++)
        o[dt] = __builtin_shufflevector(pk_mul(HALF0(o[dt]), al2),
                                        pk_mul(HALF1(o[dt]), al2), 0, 1, 2, 3);
      m_run = mn;
    }
    const f32x2 scv = {SC, SC};
    const f32x2 nm2 = {-mn, -mn};
    f32x2 p2[4][2];
#pragma unroll
    for (int nt = 0; nt < 4; nt++) {
      const f32x2 t0 = pk_fma(HALF0(sa[nt]), scv, nm2);
      const f32x2 t1 = pk_fma(HALF1(sa[nt]), scv, nm2);
      f32x2 p0; p0[0] = fexp2(t0[0]); p0[1] = fexp2(t0[1]);
      f32x2 p1; p1[0] = fexp2(t1[0]); p1[1] = fexp2(t1[1]);
      p2[nt][0] = p0;
      p2[nt][1] = p1;
    }
    f32x2 s0 = pk_add(p2[0][0], p2[0][1]);
    f32x2 s1 = pk_add(p2[1][0], p2[1][1]);
    f32x2 s2 = pk_add(p2[2][0], p2[2][1]);
    f32x2 s3 = pk_add(p2[3][0], p2[3][1]);
    s0 = pk_add(s0, s1);
    s2 = pk_add(s2, s3);
    s0 = pk_add(s0, s2);
    float sum = s0[0] + s0[1];
    sum = red4rows_sum(sum);
    l_run += sum;

    unsigned pk[4][2];
#pragma unroll
    for (int nt = 0; nt < 4; nt++) {
      pk[nt][0] = cvt_pk_bf16(p2[nt][0][0], p2[nt][0][1]);
      pk[nt][1] = cvt_pk_bf16(p2[nt][1][0], p2[nt][1][1]);
    }
    union { unsigned u[4]; bf16x8 v; } c0, c1;
    {
      auto r0 = __builtin_amdgcn_permlane32_swap(pk[0][0], pk[1][0], false, false);
      auto s0p = __builtin_amdgcn_permlane16_swap(r0[0], r0[1], false, false);
      auto r1 = __builtin_amdgcn_permlane32_swap(pk[0][1], pk[1][1], false, false);
      auto s1p = __builtin_amdgcn_permlane16_swap(r1[0], r1[1], false, false);
      c0.u[0] = s0p[0]; c0.u[1] = s1p[0]; c0.u[2] = s0p[1]; c0.u[3] = s1p[1];
      auto r2 = __builtin_amdgcn_permlane32_swap(pk[2][0], pk[3][0], false, false);
      auto s2p = __builtin_amdgcn_permlane16_swap(r2[0], r2[1], false, false);
      auto r3 = __builtin_amdgcn_permlane32_swap(pk[2][1], pk[3][1], false, false);
      auto s3p = __builtin_amdgcn_permlane16_swap(r3[0], r3[1], false, false);
      c1.u[0] = s2p[0]; c1.u[1] = s3p[0]; c1.u[2] = s2p[1]; c1.u[3] = s3p[1];
    }
    pfrag[0] = c0.v;
    pfrag[1] = c1.v;
  };

  stage(0, 0);
  __syncthreads();
  for (int jb = 0; jb <= tileB; jb++) {
    const int cur = jb & 1;
    if (jb < tileB) stage(jb + 1, cur ^ 1);
    const bool doA = (jb <= tileA);      // block-uniform

    // --- QK cluster (kf live only here) ---
    bf16x8 kf[2][4];
#pragma unroll
    for (int ks = 0; ks < 2; ks++)
#pragma unroll
      for (int nt = 0; nt < 4; nt++) {
        const int kvr = nt * 16 + lrow;
        const int blk = (ks * 4 + (lane >> 4)) ^ (kvr & 7);
        kf[ks][nt] = *(const bf16x8*)&Kl[cur][kvr * 64 + blk * 8];
      }
    f32x4 saB[4], saA[4];
    __builtin_amdgcn_s_setprio(1);
    qk(kf, qfB, saB);
    if (doA) qk(kf, qfA, saA);
    __builtin_amdgcn_s_setprio(0);

    // --- two independent softmax chains (ILP) ---
    bf16x8 pfB[2], pfA[2];
    softmax(saB, oB, mB, lB, jb == tileB, pfB);
    if (doA) softmax(saA, oA, mA, lA, jb == tileA, pfA);

    // --- vf load just before PV (short live range) ---
    bf16x8 vf[2][4];
#pragma unroll
    for (int ks = 0; ks < 2; ks++)
#pragma unroll
      for (int dt = 0; dt < 4; dt++) {
        const int vr = dt * 16 + lrow;
        const int vblk = (ks * 4 + (lane >> 4)) ^ (vr & 7);
        vf[ks][dt] = *(const bf16x8*)&Vl[cur][vr * 64 + vblk * 8];
      }

    // --- PV cluster ---
    __builtin_amdgcn_s_setprio(1);
#pragma unroll
    for (int ks = 0; ks < 2; ks++)
#pragma unroll
      for (int dt = 0; dt < 4; dt++)
        oB[dt] = __builtin_amdgcn_mfma_f32_16x16x32_bf16(vf[ks][dt], pfB[ks], oB[dt], 0, 0, 0);
    if (doA) {
#pragma unroll
      for (int ks = 0; ks < 2; ks++)
#pragma unroll
        for (int dt = 0; dt < 4; dt++)
          oA[dt] = __builtin_amdgcn_mfma_f32_16x16x32_bf16(vf[ks][dt], pfA[ks], oA[dt], 0, 0, 0);
    }
    __builtin_amdgcn_s_setprio(0);
    __syncthreads();
  }

  const int b = bh >> 4, h = bh & 15;
  const float invA = 1.0f / lA;
  const float invB = 1.0f / lB;
  const int qgA = tileA * 64 + w * 16 + lrow;
  const int qgB = tileB * 64 + w * 16 + lrow;
#pragma unroll
  for (int dt = 0; dt < 4; dt++) {
    uint2 pa, pb;
    pa.x = cvt_pk_bf16(oA[dt][0] * invA, oA[dt][1] * invA);
    pa.y = cvt_pk_bf16(oA[dt][2] * invA, oA[dt][3] * invA);
    pb.x = cvt_pk_bf16(oB[dt][0] * invB, oB[dt][1] * invB);
    pb.y = cvt_pk_bf16(oB[dt][2] * invB, oB[dt][3] * invB);
    *(uint2*)&y[(size_t)(b * S_LEN + qgA) * EMB + h * HD + dt * 16 + g4] = pa;
    *(uint2*)&y[(size_t)(b * S_LEN + qgB) * EMB + h * HD + dt * 16 + g4] = pb;
  }
}

extern "C" void kernel_launch(void* const* d_in, const int* in_sizes, int n_in,
                              void* d_out, int out_size, void* d_ws, size_t ws_size,
                              hipStream_t stream) {
  const float* x      = (const float*)d_in[0];
  const float* w_qkv  = (const float*)d_in[1];
  const float* b_qkv  = (const float*)d_in[2];
  const float* w_proj = (const float*)d_in[3];
  const float* b_proj = (const float*)d_in[4];
  float* out = (float*)d_out;

  char* ws = (char*)d_ws;
  u16* wqkvT  = (u16*)(ws);                  // 3072x1024 bf16 (6 MB)
  u16* wprojT = (u16*)(ws + 6291456);        // 1024x1024 bf16 (2 MB)
  u16* xb     = (u16*)(ws + 8388608);        // 8192x1024 bf16 (16 MB), reused as y_att
  u16* q_ws   = (u16*)(ws + 25165824);       // [B,H,S,D] bf16 (16 MB)
  u16* k_ws   = (u16*)(ws + 41943040);       // [B,H,S,D]
  u16* v_t    = (u16*)(ws + 58720256);       // [B,H,D,S] (transposed!)  end: 72 MB
  u16* y_att  = xb;                          // x dead after GEMM1

  k_prep<<<dim3(2048), dim3(256), 0, stream>>>(x, xb, w_qkv, wqkvT, w_proj, wprojT);
  k_gemm<0><<<dim3(24, 64), dim3(256), 0, stream>>>(xb, wqkvT, b_qkv, nullptr,
                                                    q_ws, k_ws, v_t, 3072, 1024);
  k_attn<<<dim3(16, 64), dim3(256), 0, stream>>>(q_ws, k_ws, v_t, y_att);
  k_gemm<1><<<dim3(8, 64), dim3(256), 0, stream>>>(y_att, wprojT, b_proj, out,
                                                   nullptr, nullptr, nullptr, 1024, 1024);
}

// Round 17
// 182.264 us; speedup vs baseline: 1.8914x; 1.0060x over previous
//
#include <hip/hip_runtime.h>
#include <hip/hip_bf16.h>
#include <stdint.h>

#define S_LEN 2048
#define EMB   1024
#define NH    16
#define HD    64

typedef unsigned short u16;
typedef __attribute__((ext_vector_type(2))) float f32x2;
typedef __attribute__((ext_vector_type(4))) float f32x4;
typedef __attribute__((ext_vector_type(8))) short bf16x8;

typedef __attribute__((address_space(1))) const unsigned char gas_t;
typedef __attribute__((address_space(3))) unsigned char las_t;

static __device__ __forceinline__ void gld_lds16(const void* g, void* l) {
  __builtin_amdgcn_global_load_lds((gas_t*)g, (las_t*)l, 16, 0, 0);
}

static __device__ __forceinline__ u16 f2bf(float f) {
  unsigned int u = __builtin_bit_cast(unsigned int, f);
  u = u + 0x7fffu + ((u >> 16) & 1u);   // RNE; inputs are finite
  return (u16)(u >> 16);
}

// exp2 in one instruction (v_exp_f32 IS 2^x). HW-validated R4/R5.
static __device__ __forceinline__ float fexp2(float x) {
  float r;
  asm("v_exp_f32 %0, %1" : "=v"(r) : "v"(x));
  return r;
}

// pack 2 f32 -> 2 bf16 (RNE); lo = first arg. HW-validated R4/R5.
static __device__ __forceinline__ unsigned cvt_pk_bf16(float lo, float hi) {
  unsigned r;
  asm("v_cvt_pk_bf16_f32 %0, %1, %2" : "=v"(r) : "v"(lo), "v"(hi));
  return r;
}

// 3-input max: genuine gfx9+ VOP3 (ISA §3). Plain VALU, no hazard concern.
// R15 lesson: v_pk_max_f32 does NOT exist on gfx950 — ISA-check each op.
static __device__ __forceinline__ float max3(float a, float b, float c) {
  float r;
  asm("v_max3_f32 %0, %1, %2, %3" : "=v"(r) : "v"(a), "v"(b), "v"(c));
  return r;
}

// Packed f32 VOP3P ops that DO exist on gfx950 (add validated R10 at runtime;
// mul/fma compile+runtime validated R16).
static __device__ __forceinline__ f32x2 pk_add(f32x2 a, f32x2 b) {
  f32x2 r;
  asm("v_pk_add_f32 %0, %1, %2" : "=v"(r) : "v"(a), "v"(b));
  return r;
}
static __device__ __forceinline__ f32x2 pk_mul(f32x2 a, f32x2 b) {
  f32x2 r;
  asm("v_pk_mul_f32 %0, %1, %2" : "=v"(r) : "v"(a), "v"(b));
  return r;
}
static __device__ __forceinline__ f32x2 pk_fma(f32x2 a, f32x2 b, f32x2 c) {
  f32x2 r;
  asm("v_pk_fma_f32 %0, %1, %2, %3" : "=v"(r) : "v"(a), "v"(b), "v"(c));
  return r;
}
#define HALF0(v) __builtin_shufflevector(v, v, 0, 1)
#define HALF1(v) __builtin_shufflevector(v, v, 2, 3)

// Permlane swaps via BUILTINS (not inline asm) — R6/R7 lesson: the
// VALU->permlane RAW hazard is only mitigated for compiler-known instrs.
static __device__ __forceinline__ float red4rows_max(float x) {
  unsigned u = __builtin_bit_cast(unsigned, x);
  auto r = __builtin_amdgcn_permlane32_swap(u, u, false, false);
  float y = fmaxf(__builtin_bit_cast(float, (unsigned)r[0]),
                  __builtin_bit_cast(float, (unsigned)r[1]));
  unsigned v = __builtin_bit_cast(unsigned, y);
  auto r2 = __builtin_amdgcn_permlane16_swap(v, v, false, false);
  return fmaxf(__builtin_bit_cast(float, (unsigned)r2[0]),
               __builtin_bit_cast(float, (unsigned)r2[1]));
}
static __device__ __forceinline__ float red4rows_sum(float x) {
  unsigned u = __builtin_bit_cast(unsigned, x);
  auto r = __builtin_amdgcn_permlane32_swap(u, u, false, false);
  float y = __builtin_bit_cast(float, (unsigned)r[0]) +
            __builtin_bit_cast(float, (unsigned)r[1]);
  unsigned v = __builtin_bit_cast(unsigned, y);
  auto r2 = __builtin_amdgcn_permlane16_swap(v, v, false, false);
  return __builtin_bit_cast(float, (unsigned)r2[0]) +
         __builtin_bit_cast(float, (unsigned)r2[1]);
}

// ---------------- fused preprocessing: x->bf16 + both weight transposes -----
// grid 2048 x 256: [0,1024) cvt, [1024,1792) w_qkv T, [1792,2048) w_proj T.
__global__ __launch_bounds__(256) void k_prep(const float* __restrict__ x,
                                              u16* __restrict__ xb,
                                              const float* __restrict__ w_qkv,
                                              u16* __restrict__ wqkvT,
                                              const float* __restrict__ w_proj,
                                              u16* __restrict__ wprojT) {
  __shared__ u16 tile[64][68];
  const int bid = blockIdx.x;
  const int t = threadIdx.x;
  if (bid < 1024) {
    const int n4 = (8192 * 1024) / 4;
    int i = bid * 256 + t;
    for (; i < n4; i += 1024 * 256) {
      float4 f = ((const float4*)x)[i];
      ushort4 o;
      o.x = f2bf(f.x); o.y = f2bf(f.y); o.z = f2bf(f.z); o.w = f2bf(f.w);
      ((ushort4*)xb)[i] = o;
    }
    return;
  }
  const float* W;
  u16* WT;
  int c0, r0, K, N;
  if (bid < 1792) {
    const int idx = bid - 1024;            // 48 x 16 blocks
    W = w_qkv; WT = wqkvT; K = 1024; N = 3072;
    c0 = (idx % 48) * 64; r0 = (idx / 48) * 64;
  } else {
    const int idx = bid - 1792;            // 16 x 16 blocks
    W = w_proj; WT = wprojT; K = 1024; N = 1024;
    c0 = (idx & 15) * 64; r0 = (idx >> 4) * 64;
  }
  const int tr = t >> 4, tc4 = (t & 15) * 4;
#pragma unroll
  for (int i = 0; i < 4; i++) {
    const int r = tr + 16 * i;
    float4 f = *(const float4*)&W[(size_t)(r0 + r) * N + c0 + tc4];
    ushort4 o;
    o.x = f2bf(f.x); o.y = f2bf(f.y); o.z = f2bf(f.z); o.w = f2bf(f.w);
    *(ushort4*)&tile[r][tc4] = o;
  }
  __syncthreads();
  const int oc = t >> 2, or0 = (t & 3) * 16;
  u16 vals[16];
#pragma unroll
  for (int j = 0; j < 16; j++) vals[j] = tile[or0 + j][oc];
  u16* dst = &WT[(size_t)(c0 + oc) * K + r0 + or0];
  *(uint4*)dst = *(const uint4*)&vals[0];
  *(uint4*)(dst + 8) = *(const uint4*)&vals[8];
}

// ---------------- GEMM: C[M,N] = A[M,K](bf16) @ BT[N,K]^T + bias ----------------
// 128x128 tile, BK=32, 4 waves, double-buffered LDS, one barrier per k-step.
// T1 XCD-chunked swizzle (validated R12). R17: setprio REMOVED (guide m190:
// measured slightly negative on lockstep 2-phase GEMM; only pays phase-split).
// MODE 0: scatter q/k bf16 [B,H,S,D], v bf16 [B,H,D,S] (transposed, vectorized).
// MODE 1: f32 out + bias.
template <int MODE>
__global__ __launch_bounds__(256) void k_gemm(const u16* __restrict__ A,
                                              const u16* __restrict__ BT,
                                              const float* __restrict__ bias,
                                              float* __restrict__ Cout,
                                              u16* __restrict__ q_ws,
                                              u16* __restrict__ k_ws,
                                              u16* __restrict__ v_t,
                                              int N, int K) {
  __shared__ u16 As[2][128 * 32];
  __shared__ u16 Bs[2][128 * 32];
  const int tid = threadIdx.x;
  const int w = tid >> 6, lane = tid & 63;
  const int wr = w >> 1, wc = w & 1;
  const int lrow = lane & 15, lk8 = (lane >> 4) * 8;
  const int orig = blockIdx.y * gridDim.x + blockIdx.x;
  const int total = gridDim.x * gridDim.y;
  const int wgid = (orig & 7) * (total >> 3) + (orig >> 3);
  const int bxn = wgid % gridDim.x;
  const int byn = wgid / gridDim.x;
  const int brow = byn * 128, bcol = bxn * 128;
  const int srow = lane >> 2;          // 0..15 within chunk
  const int scol = (lane & 3) * 8;     // 0,8,16,24

  const f32x4 zero = {0.f, 0.f, 0.f, 0.f};
  f32x4 acc[4][4];
#pragma unroll
  for (int m = 0; m < 4; m++)
#pragma unroll
    for (int n = 0; n < 4; n++) acc[m][n] = zero;

  auto stage = [&](int kt, int buf) {
#pragma unroll
    for (int i = 0; i < 2; i++) {
      const int c = w * 2 + i;               // chunk 0..7, 1KB each (linear LDS)
      const int row = c * 16 + srow;
      gld_lds16(&A[(size_t)(brow + row) * K + kt + scol], (void*)(&As[buf][c * 512]));
      gld_lds16(&BT[(size_t)(bcol + row) * K + kt + scol], (void*)(&Bs[buf][c * 512]));
    }
  };

  const int NK = K >> 5;
  stage(0, 0);
  __syncthreads();
  for (int it = 0; it < NK; ++it) {
    const int cur = it & 1;
    if (it + 1 < NK) stage((it + 1) << 5, cur ^ 1);
    bf16x8 af[4], bfr[4];
#pragma unroll
    for (int mt = 0; mt < 4; mt++)
      af[mt] = *(const bf16x8*)&As[cur][(wr * 64 + mt * 16 + lrow) * 32 + lk8];
#pragma unroll
    for (int nt = 0; nt < 4; nt++)
      bfr[nt] = *(const bf16x8*)&Bs[cur][(wc * 64 + nt * 16 + lrow) * 32 + lk8];
#pragma unroll
    for (int mt = 0; mt < 4; mt++)
#pragma unroll
      for (int nt = 0; nt < 4; nt++)
        acc[mt][nt] = __builtin_amdgcn_mfma_f32_16x16x32_bf16(af[mt], bfr[nt],
                                                              acc[mt][nt], 0, 0, 0);
    __syncthreads();
  }

  if constexpr (MODE == 0) {
    const int which = bcol >> 10;   // uniform per block (0=q, 1=k, 2=v)
#pragma unroll
    for (int mt = 0; mt < 4; mt++)
#pragma unroll
      for (int nt = 0; nt < 4; nt++) {
        const int col = bcol + wc * 64 + nt * 16 + lrow;
        const int e = col & 1023;
        const int h = e >> 6, d = e & 63;
        const int row0 = brow + wr * 64 + mt * 16 + (lane >> 4) * 4;
        const int b = row0 >> 11, s0 = row0 & 2047;
        const size_t bh = (size_t)(b * NH + h);
        const float bv = bias[col];
        if (which == 2) {
          ushort4 pk;
          pk.x = f2bf(acc[mt][nt][0] + bv);
          pk.y = f2bf(acc[mt][nt][1] + bv);
          pk.z = f2bf(acc[mt][nt][2] + bv);
          pk.w = f2bf(acc[mt][nt][3] + bv);
          *(ushort4*)&v_t[(bh * HD + d) * S_LEN + s0] = pk;
        } else {
          u16* dst = which ? k_ws : q_ws;
#pragma unroll
          for (int r = 0; r < 4; r++)
            dst[(bh * S_LEN + s0 + r) * HD + d] = f2bf(acc[mt][nt][r] + bv);
        }
      }
  } else {
#pragma unroll
    for (int mt = 0; mt < 4; mt++)
#pragma unroll
      for (int nt = 0; nt < 4; nt++)
#pragma unroll
        for (int r = 0; r < 4; r++) {
          const int row = brow + wr * 64 + mt * 16 + (lane >> 4) * 4 + r;
          const int col = bcol + wc * 64 + nt * 16 + lrow;
          Cout[(size_t)row * N + col] = acc[mt][nt][r] + bias[col];
        }
  }
}

// ---------------- causal flash attention ------------------------------------
// grid (16, B*H), 256 threads, pair-balanced {pr, 31-pr}, K/V double-buffered
// in LDS (R13 lesson: staging amortizes loads across waves + gives full-tile
// prefetch distance). SWAPPED QK^T -> S[kv][q]; P in registers via cvt_pk +
// permlane routing; PV = mfma(V^T, P) -> O[d][q]. XCD remap (R12).
// R17: vf LDS reads ISSUED BEFORE the softmax chains (T14 issue-early /
// consume-late) — their lgkmcnt clears under ~300cy of softmax VALU instead
// of stalling PV entry. VGPR rises ~76->110, still 4 waves/SIMD.
__global__ __launch_bounds__(256, 2) void k_attn(const u16* __restrict__ q_ws,
                                                 const u16* __restrict__ k_ws,
                                                 const u16* __restrict__ v_t,
                                                 u16* __restrict__ y) {
  __shared__ u16 Kl[2][64 * 64];     // XOR-swizzled rows (16B blocks), [kv][d]
  __shared__ u16 Vl[2][64 * 64];     // XOR-swizzled rows, [d][kv]
  const int tid = threadIdx.x;
  const int w = tid >> 6, lane = tid & 63;
  const int lrow = lane & 15, lk8 = (lane >> 4) * 8;
  const int g4 = (lane >> 4) * 4;
  const int mthr = w * 16 + lrow - g4;     // mask: kv-local nt*16+r > mthr
  // XCD-aware remap: f = (bh&7) + 8*pr + 128*(bh>>3)  (bijective over 1024)
  const int f = blockIdx.y * 16 + blockIdx.x;
  const int pr = (f >> 3) & 15;            // 0..15
  const int bh = (f & 7) + ((f >> 7) << 3);
  const int tileA = pr, tileB = 31 - pr;   // tileA < tileB, work = const 33
  const size_t base = (size_t)bh * S_LEN * HD;
  const float SC = 0.125f * 1.4426950408889634f;  // D^-0.5 * log2(e)

  bf16x8 qfA[2], qfB[2];
#pragma unroll
  for (int ks = 0; ks < 2; ks++) {
    qfA[ks] = *(const bf16x8*)&q_ws[base + (size_t)(tileA * 64 + w * 16 + lrow) * HD + ks * 32 + lk8];
    qfB[ks] = *(const bf16x8*)&q_ws[base + (size_t)(tileB * 64 + w * 16 + lrow) * HD + ks * 32 + lk8];
  }

  const f32x4 zero = {0.f, 0.f, 0.f, 0.f};
  f32x4 oA[4], oB[4];                 // O[d][q]: d = dt*16 + g4 + r, q = lrow
#pragma unroll
  for (int dt = 0; dt < 4; dt++) { oA[dt] = zero; oB[dt] = zero; }
  float mA = -1e30f, lA = 0.f, mB = -1e30f, lB = 0.f;

  auto stage = [&](int jb, int buf) {
#pragma unroll
    for (int i = 0; i < 2; i++) {
      const int c = w * 2 + i;
      const int row = c * 8 + (lane >> 3);
      const int blk = (lane & 7) ^ (row & 7);
      gld_lds16(&k_ws[base + (size_t)(jb * 64 + row) * HD + blk * 8],
                (void*)(&Kl[buf][c * 512]));
      gld_lds16(&v_t[base + (size_t)row * S_LEN + jb * 64 + blk * 8],
                (void*)(&Vl[buf][c * 512]));
    }
  };

  // QK^T only: sa[nt][r] = S[kv = nt*16+g4+r][q = lrow]
  auto qk = [&](const bf16x8 (&kf)[2][4], const bf16x8 (&qf)[2], f32x4 (&sa)[4]) {
#pragma unroll
    for (int nt = 0; nt < 4; nt++) sa[nt] = zero;
#pragma unroll
    for (int ks = 0; ks < 2; ks++)
#pragma unroll
      for (int nt = 0; nt < 4; nt++)
        sa[nt] = __builtin_amdgcn_mfma_f32_16x16x32_bf16(kf[ks][nt], qf[ks], sa[nt], 0, 0, 0);
  };

  // softmax + P-pack: mutates sa in place, produces pfrag; updates o/m/l.
  auto softmax = [&](f32x4 (&sa)[4], f32x4 (&o)[4], float& m_run, float& l_run,
                     bool maskDiag, bf16x8 (&pfrag)[2]) {
    if (maskDiag) {
#pragma unroll
      for (int nt = 0; nt < 4; nt++)
#pragma unroll
        for (int r = 0; r < 4; r++)
          if (nt * 16 + r > mthr) sa[nt][r] = -3.0e38f;
    }

    // v_max3 tree: 7 max3 + 1 fmax (was 15 fmax); exact max, order-free
    const float m0 = max3(sa[0][0], sa[0][1], sa[0][2]);
    const float m1 = max3(sa[0][3], sa[1][0], sa[1][1]);
    const float m2 = max3(sa[1][2], sa[1][3], sa[2][0]);
    const float m3 = max3(sa[2][1], sa[2][2], sa[2][3]);
    const float m4 = max3(sa[3][0], sa[3][1], sa[3][2]);
    const float m5 = max3(m0, m1, m2);
    const float m6 = max3(m3, m4, sa[3][3]);
    float mx = fmaxf(m5, m6);
    mx = red4rows_max(mx);
    const float mxs = mx * SC;
    const bool nogrow = __all(mxs <= m_run + 8.0f);   // defer-max (T13)
    float mn = m_run;
    if (!nogrow) {
      mn = fmaxf(m_run, mxs);
      const float alpha = fexp2(m_run - mn);
      l_run *= alpha;
      const f32x2 al2 = {alpha, alpha};
#pragma unroll
      for (int dt = 0; dt < 4; dt++)
        o[dt] = __builtin_shufflevector(pk_mul(HALF0(o[dt]), al2),
                                        pk_mul(HALF1(o[dt]), al2), 0, 1, 2, 3);
      m_run = mn;
    }
    const f32x2 scv = {SC, SC};
    const f32x2 nm2 = {-mn, -mn};
    f32x2 p2[4][2];
#pragma unroll
    for (int nt = 0; nt < 4; nt++) {
      const f32x2 t0 = pk_fma(HALF0(sa[nt]), scv, nm2);
      const f32x2 t1 = pk_fma(HALF1(sa[nt]), scv, nm2);
      f32x2 p0; p0[0] = fexp2(t0[0]); p0[1] = fexp2(t0[1]);
      f32x2 p1; p1[0] = fexp2(t1[0]); p1[1] = fexp2(t1[1]);
      p2[nt][0] = p0;
      p2[nt][1] = p1;
    }
    f32x2 s0 = pk_add(p2[0][0], p2[0][1]);
    f32x2 s1 = pk_add(p2[1][0], p2[1][1]);
    f32x2 s2 = pk_add(p2[2][0], p2[2][1]);
    f32x2 s3 = pk_add(p2[3][0], p2[3][1]);
    s0 = pk_add(s0, s1);
    s2 = pk_add(s2, s3);
    s0 = pk_add(s0, s2);
    float sum = s0[0] + s0[1];
    sum = red4rows_sum(sum);
    l_run += sum;

    unsigned pk[4][2];
#pragma unroll
    for (int nt = 0; nt < 4; nt++) {
      pk[nt][0] = cvt_pk_bf16(p2[nt][0][0], p2[nt][0][1]);
      pk[nt][1] = cvt_pk_bf16(p2[nt][1][0], p2[nt][1][1]);
    }
    union { unsigned u[4]; bf16x8 v; } c0, c1;
    {
      auto r0 = __builtin_amdgcn_permlane32_swap(pk[0][0], pk[1][0], false, false);
      auto s0p = __builtin_amdgcn_permlane16_swap(r0[0], r0[1], false, false);
      auto r1 = __builtin_amdgcn_permlane32_swap(pk[0][1], pk[1][1], false, false);
      auto s1p = __builtin_amdgcn_permlane16_swap(r1[0], r1[1], false, false);
      c0.u[0] = s0p[0]; c0.u[1] = s1p[0]; c0.u[2] = s0p[1]; c0.u[3] = s1p[1];
      auto r2 = __builtin_amdgcn_permlane32_swap(pk[2][0], pk[3][0], false, false);
      auto s2p = __builtin_amdgcn_permlane16_swap(r2[0], r2[1], false, false);
      auto r3 = __builtin_amdgcn_permlane32_swap(pk[2][1], pk[3][1], false, false);
      auto s3p = __builtin_amdgcn_permlane16_swap(r3[0], r3[1], false, false);
      c1.u[0] = s2p[0]; c1.u[1] = s3p[0]; c1.u[2] = s2p[1]; c1.u[3] = s3p[1];
    }
    pfrag[0] = c0.v;
    pfrag[1] = c1.v;
  };

  stage(0, 0);
  __syncthreads();
  for (int jb = 0; jb <= tileB; jb++) {
    const int cur = jb & 1;
    if (jb < tileB) stage(jb + 1, cur ^ 1);
    const bool doA = (jb <= tileA);      // block-uniform

    // --- QK cluster (kf live only here) ---
    bf16x8 kf[2][4];
#pragma unroll
    for (int ks = 0; ks < 2; ks++)
#pragma unroll
      for (int nt = 0; nt < 4; nt++) {
        const int kvr = nt * 16 + lrow;
        const int blk = (ks * 4 + (lane >> 4)) ^ (kvr & 7);
        kf[ks][nt] = *(const bf16x8*)&Kl[cur][kvr * 64 + blk * 8];
      }
    f32x4 saB[4], saA[4];
    __builtin_amdgcn_s_setprio(1);
    qk(kf, qfB, saB);
    if (doA) qk(kf, qfA, saA);
    __builtin_amdgcn_s_setprio(0);

    // --- vf ISSUED EARLY (T14): lgkmcnt clears under the softmax chains ---
    bf16x8 vf[2][4];
#pragma unroll
    for (int ks = 0; ks < 2; ks++)
#pragma unroll
      for (int dt = 0; dt < 4; dt++) {
        const int vr = dt * 16 + lrow;
        const int vblk = (ks * 4 + (lane >> 4)) ^ (vr & 7);
        vf[ks][dt] = *(const bf16x8*)&Vl[cur][vr * 64 + vblk * 8];
      }

    // --- two independent softmax chains (ILP) ---
    bf16x8 pfB[2], pfA[2];
    softmax(saB, oB, mB, lB, jb == tileB, pfB);
    if (doA) softmax(saA, oA, mA, lA, jb == tileA, pfA);

    // --- PV cluster ---
    __builtin_amdgcn_s_setprio(1);
#pragma unroll
    for (int ks = 0; ks < 2; ks++)
#pragma unroll
      for (int dt = 0; dt < 4; dt++)
        oB[dt] = __builtin_amdgcn_mfma_f32_16x16x32_bf16(vf[ks][dt], pfB[ks], oB[dt], 0, 0, 0);
    if (doA) {
#pragma unroll
      for (int ks = 0; ks < 2; ks++)
#pragma unroll
        for (int dt = 0; dt < 4; dt++)
          oA[dt] = __builtin_amdgcn_mfma_f32_16x16x32_bf16(vf[ks][dt], pfA[ks], oA[dt], 0, 0, 0);
    }
    __builtin_amdgcn_s_setprio(0);
    __syncthreads();
  }

  const int b = bh >> 4, h = bh & 15;
  const float invA = 1.0f / lA;
  const float invB = 1.0f / lB;
  const int qgA = tileA * 64 + w * 16 + lrow;
  const int qgB = tileB * 64 + w * 16 + lrow;
#pragma unroll
  for (int dt = 0; dt < 4; dt++) {
    uint2 pa, pb;
    pa.x = cvt_pk_bf16(oA[dt][0] * invA, oA[dt][1] * invA);
    pa.y = cvt_pk_bf16(oA[dt][2] * invA, oA[dt][3] * invA);
    pb.x = cvt_pk_bf16(oB[dt][0] * invB, oB[dt][1] * invB);
    pb.y = cvt_pk_bf16(oB[dt][2] * invB, oB[dt][3] * invB);
    *(uint2*)&y[(size_t)(b * S_LEN + qgA) * EMB + h * HD + dt * 16 + g4] = pa;
    *(uint2*)&y[(size_t)(b * S_LEN + qgB) * EMB + h * HD + dt * 16 + g4] = pb;
  }
}

extern "C" void kernel_launch(void* const* d_in, const int* in_sizes, int n_in,
                              void* d_out, int out_size, void* d_ws, size_t ws_size,
                              hipStream_t stream) {
  const float* x      = (const float*)d_in[0];
  const float* w_qkv  = (const float*)d_in[1];
  const float* b_qkv  = (const float*)d_in[2];
  const float* w_proj = (const float*)d_in[3];
  const float* b_proj = (const float*)d_in[4];
  float* out = (float*)d_out;

  char* ws = (char*)d_ws;
  u16* wqkvT  = (u16*)(ws);                  // 3072x1024 bf16 (6 MB)
  u16* wprojT = (u16*)(ws + 6291456);        // 1024x1024 bf16 (2 MB)
  u16* xb     = (u16*)(ws + 8388608);        // 8192x1024 bf16 (16 MB), reused as y_att
  u16* q_ws   = (u16*)(ws + 25165824);       // [B,H,S,D] bf16 (16 MB)
  u16* k_ws   = (u16*)(ws + 41943040);       // [B,H,S,D]
  u16* v_t    = (u16*)(ws + 58720256);       // [B,H,D,S] (transposed!)  end: 72 MB
  u16* y_att  = xb;                          // x dead after GEMM1

  k_prep<<<dim3(2048), dim3(256), 0, stream>>>(x, xb, w_qkv, wqkvT, w_proj, wprojT);
  k_gemm<0><<<dim3(24, 64), dim3(256), 0, stream>>>(xb, wqkvT, b_qkv, nullptr,
                                                    q_ws, k_ws, v_t, 3072, 1024);
  k_attn<<<dim3(16, 64), dim3(256), 0, stream>>>(q_ws, k_ws, v_t, y_att);
  k_gemm<1><<<dim3(8, 64), dim3(256), 0, stream>>>(y_att, wprojT, b_proj, out,
                                                   nullptr, nullptr, nullptr, 1024, 1024);
}